// Round 1
// baseline (717.220 us; speedup 1.0000x reference)
//
#include <hip/hip_runtime.h>

// ---------------------------------------------------------------------------
// Cluster_51342039056604 — fp32 reference-faithful implementation (round 1).
// K1: fused feat+value 1x1 conv GEMM (fp32, 128x128x16 tiles, 8x8/thread)
// K2: per-folded-batch clustering (centers, cos/sim, argmax, losses, outp)
// K3: proj 1x1 conv GEMM + loss finalize
// outp is written in-place over the feat workspace (disjoint per-block slices).
// ---------------------------------------------------------------------------

#define HW 1024   // 32*32 pixels per image

// swizzled LDS index for the [256 pt][64 ch] tile: conflict-free for
// (a) per-lane-n column reads, (b) per-lane-c row reads, (c) float4-over-n writes
__device__ __forceinline__ int sw_idx(int n, int c) {
    return n * 64 + (c ^ (((n >> 2) ^ n) & 31));
}

// ---------------- K1: feat/value conv ----------------
// grid (p_tiles=8, o_tiles=8, b=32), block 256. o<512 -> feat, else value.
__global__ __launch_bounds__(256) void k_conv_fv(
    const float* __restrict__ x,
    const float* __restrict__ f_w, const float* __restrict__ f_b,
    const float* __restrict__ v_w, const float* __restrict__ v_b,
    float* __restrict__ feat_ws, float* __restrict__ value_ws)
{
    __shared__ float As[16][128];   // [k][o]
    __shared__ float Bs[16][128];   // [k][p]
    const int t = threadIdx.x;
    const int b = blockIdx.z;
    const int o0 = blockIdx.y * 128;
    const int p0 = blockIdx.x * 128;

    const float* W    = (o0 < 512) ? f_w : v_w;
    const float* bias = (o0 < 512) ? f_b : v_b;
    float* out        = (o0 < 512) ? feat_ws : value_ws;
    const int oo = o0 & 511;
    const float* Xb = x + (size_t)b * (512 * HW);

    float acc[8][8];
#pragma unroll
    for (int i = 0; i < 8; ++i)
#pragma unroll
        for (int j = 0; j < 8; ++j) acc[i][j] = 0.f;

    const int row_a = t >> 1, col_a = (t & 1) * 8;   // A stage: 128 rows x 16 cols
    const int row_b = t >> 4, col_b = (t & 15) * 8;  // B stage: 16 rows x 128 cols
    const int lane = t & 63, wave = t >> 6;
    const int of = (wave >> 1) * 64 + (lane >> 3) * 8;  // o fragment base
    const int pf = (wave & 1) * 64 + (lane & 7) * 8;    // p fragment base

    for (int kb = 0; kb < 32; ++kb) {
        const int k0 = kb * 16;
        const float4 a0 = *(const float4*)&W[(oo + row_a) * 512 + k0 + col_a];
        const float4 a1 = *(const float4*)&W[(oo + row_a) * 512 + k0 + col_a + 4];
        const float4 b0 = *(const float4*)&Xb[(size_t)(k0 + row_b) * HW + p0 + col_b];
        const float4 b1 = *(const float4*)&Xb[(size_t)(k0 + row_b) * HW + p0 + col_b + 4];
        __syncthreads();   // previous iteration's LDS reads complete
        As[col_a + 0][row_a] = a0.x;
        As[col_a + 1][row_a] = a0.y;
        As[col_a + 2][row_a] = a0.z;
        As[col_a + 3][row_a] = a0.w;
        As[col_a + 4][row_a] = a1.x;
        As[col_a + 5][row_a] = a1.y;
        As[col_a + 6][row_a] = a1.z;
        As[col_a + 7][row_a] = a1.w;
        *(float4*)&Bs[row_b][col_b]     = b0;
        *(float4*)&Bs[row_b][col_b + 4] = b1;
        __syncthreads();
#pragma unroll
        for (int k = 0; k < 16; ++k) {
            float av[8], bv[8];
            *(float4*)&av[0] = *(const float4*)&As[k][of];
            *(float4*)&av[4] = *(const float4*)&As[k][of + 4];
            *(float4*)&bv[0] = *(const float4*)&Bs[k][pf];
            *(float4*)&bv[4] = *(const float4*)&Bs[k][pf + 4];
#pragma unroll
            for (int i = 0; i < 8; ++i)
#pragma unroll
                for (int j = 0; j < 8; ++j) acc[i][j] = fmaf(av[i], bv[j], acc[i][j]);
        }
    }
#pragma unroll
    for (int i = 0; i < 8; ++i) {
        const int o = oo + of + i;
        const float bsv = bias[o];
        float4 r0 = make_float4(acc[i][0] + bsv, acc[i][1] + bsv, acc[i][2] + bsv, acc[i][3] + bsv);
        float4 r1 = make_float4(acc[i][4] + bsv, acc[i][5] + bsv, acc[i][6] + bsv, acc[i][7] + bsv);
        float* dst = out + ((size_t)b * 512 + o) * HW + p0 + pf;
        *(float4*)dst       = r0;
        *(float4*)(dst + 4) = r1;
    }
}

// ---------------- K2: clustering ----------------
// one block per folded batch b' = ((b*8+head)*2+f1)*2+f2; 256 threads = 256 pts
__global__ __launch_bounds__(256) void k_cluster(
    float* __restrict__ feat_ws,            // in: feat, out: outp (in place)
    const float* __restrict__ value_ws,
    const float* __restrict__ alpha_p, const float* __restrict__ beta_p,
    float* __restrict__ part)               // [3*1024] loss partials
{
    __shared__ float buf[256 * 64];   // 64 KB swizzled point-major tile
    __shared__ float cbuf[4 * 64];    // centers, later cluster outputs
    __shared__ float cinv[4];
    __shared__ int   sidx[256];
    __shared__ float red[8];
    __shared__ float gsc[16];

    const int t = threadIdx.x;
    const int lane = t & 63, wave = t >> 6;
    const int bp = blockIdx.x;
    const int f2 = bp & 1, f1 = (bp >> 1) & 1, head = (bp >> 2) & 7, b = bp >> 5;
    const size_t base = ((size_t)b * 512 + head * 64) * HW + f1 * 512 + f2 * 16;

    // ---- stage feat: float4 along h ----
#pragma unroll
    for (int i = 0; i < 16; ++i) {
        const int q = i * 256 + t;          // 0..4095 quads
        const int c = q >> 6;
        const int n0 = (q & 63) * 4;
        const float4 v = *(const float4*)&feat_ws[base + (size_t)c * HW + (n0 >> 4) * 32 + (n0 & 15)];
        buf[sw_idx(n0 + 0, c)] = v.x;
        buf[sw_idx(n0 + 1, c)] = v.y;
        buf[sw_idx(n0 + 2, c)] = v.z;
        buf[sw_idx(n0 + 3, c)] = v.w;
    }
    __syncthreads();

    // ---- centers: thread (m = t>>6, cc = t&63) ----
    const int m = t >> 6, cc = t & 63;
    const int pi = m >> 1, pj = m & 1;
    float cs = 0.f;
#pragma unroll
    for (int wp = 0; wp < 8; ++wp)
#pragma unroll
        for (int hp = 0; hp < 8; ++hp) {
            const int nn = (pi * 8 + wp) * 16 + pj * 8 + hp;
            cs += buf[sw_idx(nn, cc)];
        }
    const float cv = cs * (1.f / 64.f);
    cbuf[m * 64 + cc] = cv;
    float ssc = cv * cv;
#pragma unroll
    for (int off = 32; off > 0; off >>= 1) ssc += __shfl_xor(ssc, off);
    if (lane == 0) cinv[m] = 1.f / fmaxf(sqrtf(ssc), 1e-12f);
    __syncthreads();

    // ---- G / L_Orth partial ----
    if (t < 16) {
        const int gm = t >> 2, gk = t & 3;
        float g = 0.f;
        for (int c = 0; c < 64; ++c) g += cbuf[gm * 64 + c] * cbuf[gk * 64 + c];
        g *= cinv[gm] * cinv[gk];
        const float d = g - (gm == gk ? 1.f : 0.f);
        gsc[t] = d * d;
    }

    // ---- per-point cos/sim/argmax ----
    const float alpha = alpha_p[0], beta = beta_p[0];
    const int n = t;
    float ssf = 0.f, dot0 = 0.f, dot1 = 0.f, dot2 = 0.f, dot3 = 0.f;
    for (int c = 0; c < 64; ++c) {
        const float fv = buf[sw_idx(n, c)];
        ssf += fv * fv;
        dot0 = fmaf(fv, cbuf[0 * 64 + c], dot0);
        dot1 = fmaf(fv, cbuf[1 * 64 + c], dot1);
        dot2 = fmaf(fv, cbuf[2 * 64 + c], dot2);
        dot3 = fmaf(fv, cbuf[3 * 64 + c], dot3);
    }
    const float invf = 1.f / fmaxf(sqrtf(ssf), 1e-12f);
    float simv[4];
    simv[0] = dot0 * invf * cinv[0];
    simv[1] = dot1 * invf * cinv[1];
    simv[2] = dot2 * invf * cinv[2];
    simv[3] = dot3 * invf * cinv[3];
#pragma unroll
    for (int mm = 0; mm < 4; ++mm) {
        const float z = beta + alpha * simv[mm];
        simv[mm] = 1.f / (1.f + expf(-z));
    }
    float best = simv[0], second = -1.f;
    int idx = 0;
#pragma unroll
    for (int mm = 1; mm < 4; ++mm) {
        if (simv[mm] > best) { second = best; best = simv[mm]; idx = mm; }
        else second = fmaxf(second, simv[mm]);
    }
    sidx[n] = idx;

    float bsum = best, s2sum = second;
#pragma unroll
    for (int off = 32; off > 0; off >>= 1) {
        bsum += __shfl_xor(bsum, off);
        s2sum += __shfl_xor(s2sum, off);
    }
    if (lane == 0) { red[wave] = bsum; red[4 + wave] = s2sum; }
    __syncthreads();   // covers gsc, red, and completion of all feat-buf reads
    if (t == 0) {
        part[bp]        = gsc[0] + gsc[1] + gsc[2] + gsc[3] + gsc[4] + gsc[5] + gsc[6] + gsc[7]
                        + gsc[8] + gsc[9] + gsc[10] + gsc[11] + gsc[12] + gsc[13] + gsc[14] + gsc[15];
        part[1024 + bp] = red[0] + red[1] + red[2] + red[3];
        part[2048 + bp] = red[4] + red[5] + red[6] + red[7];
    }

    // ---- stage value over buf ----
#pragma unroll
    for (int i = 0; i < 16; ++i) {
        const int q = i * 256 + t;
        const int c = q >> 6;
        const int n0 = (q & 63) * 4;
        const float4 v = *(const float4*)&value_ws[base + (size_t)c * HW + (n0 >> 4) * 32 + (n0 & 15)];
        buf[sw_idx(n0 + 0, c)] = v.x;
        buf[sw_idx(n0 + 1, c)] = v.y;
        buf[sw_idx(n0 + 2, c)] = v.z;
        buf[sw_idx(n0 + 3, c)] = v.w;
    }
    __syncthreads();

    // ---- value centers + agg + out: thread (m, cc) ----
    float vcs = 0.f;
#pragma unroll
    for (int wp = 0; wp < 8; ++wp)
#pragma unroll
        for (int hp = 0; hp < 8; ++hp) {
            const int nn = (pi * 8 + wp) * 16 + pj * 8 + hp;
            vcs += buf[sw_idx(nn, cc)];
        }
    const float vc = vcs * (1.f / 64.f);
    float agg = 0.f;
    int cnt = 0;
    for (int nn = 0; nn < 256; ++nn) {
        if (sidx[nn] == m) { agg += buf[sw_idx(nn, cc)]; ++cnt; }  // wave-uniform branch
    }
    cbuf[m * 64 + cc] = (agg + vc) / (float)(cnt + 1);
    __syncthreads();

    // ---- outp = best * out[idx] (in place over feat_ws) ----
    for (int c = 0; c < 64; ++c) {
        const float val = best * cbuf[idx * 64 + c];
        feat_ws[base + (size_t)c * HW + (n >> 4) * 32 + (n & 15)] = val;
    }
}

// ---------------- K3: proj conv + loss finalize ----------------
// grid (p_tiles=8, o_tiles=4, b=32)
__global__ __launch_bounds__(256) void k_proj(
    const float* __restrict__ xp,   // outp natural layout (feat_ws)
    const float* __restrict__ p_w, const float* __restrict__ p_b,
    const float* __restrict__ part,
    float* __restrict__ dout)
{
    __shared__ float As[16][128];
    __shared__ float Bs[16][128];
    __shared__ float fin[12];
    const int t = threadIdx.x;

    if (blockIdx.x == 0 && blockIdx.y == 0 && blockIdx.z == 0) {
        float so = part[t] + part[t + 256] + part[t + 512] + part[t + 768];
        float sc = part[1024 + t] + part[1280 + t] + part[1536 + t] + part[1792 + t];
        float sp = part[2048 + t] + part[2304 + t] + part[2560 + t] + part[2816 + t];
        const int lane = t & 63, wave = t >> 6;
#pragma unroll
        for (int off = 32; off > 0; off >>= 1) {
            so += __shfl_xor(so, off);
            sc += __shfl_xor(sc, off);
            sp += __shfl_xor(sp, off);
        }
        if (lane == 0) { fin[wave] = so; fin[4 + wave] = sc; fin[8 + wave] = sp; }
        __syncthreads();
        if (t == 0) {
            dout[16777216]     = (fin[0] + fin[1] + fin[2] + fin[3]) / 16384.f;
            dout[16777216 + 1] = -(fin[4] + fin[5] + fin[6] + fin[7]) / 262144.f;
            dout[16777216 + 2] = (fin[8] + fin[9] + fin[10] + fin[11]) / 262144.f;
        }
    }

    const int b = blockIdx.z;
    const int o0 = blockIdx.y * 128;
    const int p0 = blockIdx.x * 128;
    const float* Xb = xp + (size_t)b * (512 * HW);

    float acc[8][8];
#pragma unroll
    for (int i = 0; i < 8; ++i)
#pragma unroll
        for (int j = 0; j < 8; ++j) acc[i][j] = 0.f;

    const int row_a = t >> 1, col_a = (t & 1) * 8;
    const int row_b = t >> 4, col_b = (t & 15) * 8;
    const int lane = t & 63, wave = t >> 6;
    const int of = (wave >> 1) * 64 + (lane >> 3) * 8;
    const int pf = (wave & 1) * 64 + (lane & 7) * 8;

    for (int kb = 0; kb < 32; ++kb) {
        const int k0 = kb * 16;
        const float4 a0 = *(const float4*)&p_w[(o0 + row_a) * 512 + k0 + col_a];
        const float4 a1 = *(const float4*)&p_w[(o0 + row_a) * 512 + k0 + col_a + 4];
        const float4 b0 = *(const float4*)&Xb[(size_t)(k0 + row_b) * HW + p0 + col_b];
        const float4 b1 = *(const float4*)&Xb[(size_t)(k0 + row_b) * HW + p0 + col_b + 4];
        __syncthreads();
        As[col_a + 0][row_a] = a0.x;
        As[col_a + 1][row_a] = a0.y;
        As[col_a + 2][row_a] = a0.z;
        As[col_a + 3][row_a] = a0.w;
        As[col_a + 4][row_a] = a1.x;
        As[col_a + 5][row_a] = a1.y;
        As[col_a + 6][row_a] = a1.z;
        As[col_a + 7][row_a] = a1.w;
        *(float4*)&Bs[row_b][col_b]     = b0;
        *(float4*)&Bs[row_b][col_b + 4] = b1;
        __syncthreads();
#pragma unroll
        for (int k = 0; k < 16; ++k) {
            float av[8], bv[8];
            *(float4*)&av[0] = *(const float4*)&As[k][of];
            *(float4*)&av[4] = *(const float4*)&As[k][of + 4];
            *(float4*)&bv[0] = *(const float4*)&Bs[k][pf];
            *(float4*)&bv[4] = *(const float4*)&Bs[k][pf + 4];
#pragma unroll
            for (int i = 0; i < 8; ++i)
#pragma unroll
                for (int j = 0; j < 8; ++j) acc[i][j] = fmaf(av[i], bv[j], acc[i][j]);
        }
    }
#pragma unroll
    for (int i = 0; i < 8; ++i) {
        const int o = o0 + of + i;
        const float bsv = p_b[o];
        float4 r0 = make_float4(acc[i][0] + bsv, acc[i][1] + bsv, acc[i][2] + bsv, acc[i][3] + bsv);
        float4 r1 = make_float4(acc[i][4] + bsv, acc[i][5] + bsv, acc[i][6] + bsv, acc[i][7] + bsv);
        float* dst = dout + ((size_t)b * 512 + o) * HW + p0 + pf;
        *(float4*)dst       = r0;
        *(float4*)(dst + 4) = r1;
    }
}

extern "C" void kernel_launch(void* const* d_in, const int* in_sizes, int n_in,
                              void* d_out, int out_size, void* d_ws, size_t ws_size,
                              hipStream_t stream)
{
    const float* x   = (const float*)d_in[0];
    const float* f_w = (const float*)d_in[1];
    const float* f_b = (const float*)d_in[2];
    const float* v_w = (const float*)d_in[3];
    const float* v_b = (const float*)d_in[4];
    const float* p_w = (const float*)d_in[5];
    const float* p_b = (const float*)d_in[6];
    const float* s_a = (const float*)d_in[7];
    const float* s_b = (const float*)d_in[8];
    float* out = (float*)d_out;

    float* feat_ws  = (float*)d_ws;             // 16777216 floats (64 MB)
    float* value_ws = feat_ws + 16777216;       // 16777216 floats (64 MB)
    float* part     = value_ws + 16777216;      // 3072 floats

    k_conv_fv<<<dim3(8, 8, 32), 256, 0, stream>>>(x, f_w, f_b, v_w, v_b, feat_ws, value_ws);
    k_cluster<<<dim3(1024), 256, 0, stream>>>(feat_ws, value_ws, s_a, s_b, part);
    k_proj<<<dim3(8, 4, 32), 256, 0, stream>>>(feat_ws, p_w, p_b, part, out);
}

// Round 2
// 294.331 us; speedup vs baseline: 2.4368x; 2.4368x over previous
//
#include <hip/hip_runtime.h>

// ---------------------------------------------------------------------------
// Round 2: MFMA (fp16x2 split) GEMMs.
//  k_xsplit : x [b][k][n] fp32 -> xh/xl [b][n][k] fp16 (scaled by 2^8, Dekker)
//  k_feat   : feat = f_w @ x, 3-term split MFMA (hi*hi + hi*lo + lo*hi), fp32 out
//  k_value  : value = v_w @ x, 1-term MFMA, fp16 out [b][o][n]
//  k_cluster: unchanged clustering; writes outpT [b][p][k] fp16
//  k_proj   : proj = p_w @ outp, 1-term MFMA, fp32 out + loss finalize
// ws layout (128 MB + 12 KB, lifetime-overlapped):
//  [0,64)MB feat | [64,96)MB xh -> outpT | [96,128)MB xl -> value_h | +12KB part
// ---------------------------------------------------------------------------

#define HW 1024

typedef _Float16 f16x8 __attribute__((ext_vector_type(8)));
typedef float f32x4 __attribute__((ext_vector_type(4)));

union H4 { uint2 u; _Float16 h[4]; };
union H2 { unsigned int u; _Float16 h[2]; };
union F4 { float4 v; float f[4]; };

__device__ __forceinline__ void gld16(const _Float16* g, _Float16* l) {
    __builtin_amdgcn_global_load_lds(
        (const __attribute__((address_space(1))) void*)g,
        (__attribute__((address_space(3))) void*)l, 16, 0, 0);
}

// swizzled LDS index for K2's [256 pt][64 ch] tile (unchanged from round 1)
__device__ __forceinline__ int sw_idx(int n, int c) {
    return n * 64 + (c ^ (((n >> 2) ^ n) & 31));
}

// ---------------- k_xsplit: transpose + fp16 split ----------------
// grid (16 n-tiles, 8 k-tiles, 32 b), block 256
__global__ __launch_bounds__(256) void k_xsplit(
    const float* __restrict__ x,
    _Float16* __restrict__ xh, _Float16* __restrict__ xl)
{
    __shared__ float tile[64][65];
    const int t = threadIdx.x;
    const int b = blockIdx.z;
    const int k0 = blockIdx.y * 64;
    const int n0 = blockIdx.x * 64;
    const float* Xb = x + (size_t)b * (512 * HW);

#pragma unroll
    for (int j = 0; j < 16; ++j) {
        const int k = j * 4 + (t >> 6);
        const int n = t & 63;
        tile[k][n] = Xb[(size_t)(k0 + k) * HW + n0 + n];
    }
    __syncthreads();
#pragma unroll
    for (int j = 0; j < 8; ++j) {
        const int n = j * 8 + (t >> 5);
        const int kp = t & 31;
        const float s0 = tile[kp * 2][n] * 256.f;
        const float s1 = tile[kp * 2 + 1][n] * 256.f;
        H2 hh, hl;
        hh.h[0] = (_Float16)s0;
        hh.h[1] = (_Float16)s1;
        hl.h[0] = (_Float16)(s0 - (float)hh.h[0]);
        hl.h[1] = (_Float16)(s1 - (float)hh.h[1]);
        const size_t o = ((size_t)b * 1024 + n0 + n) * 512 + k0 + kp * 2;
        *(unsigned int*)&xh[o] = hh.u;
        *(unsigned int*)&xl[o] = hl.u;
    }
}

// ---------------- k_feat: 3-term split MFMA GEMM ----------------
// grid (8 p-tiles, 4 o-tiles, 32 b), block 256 (4 waves, 2x2 wave grid)
__global__ __launch_bounds__(256) void k_feat(
    const float* __restrict__ w, const float* __restrict__ bias,
    const _Float16* __restrict__ xh, const _Float16* __restrict__ xl,
    float* __restrict__ feat)
{
    __shared__ _Float16 Ah[128 * 32], Al[128 * 32], Bh[128 * 32], Bl[128 * 32];
    const int t = threadIdx.x, lane = t & 63, wv = t >> 6;
    const int b = blockIdx.z, o0 = blockIdx.y * 128, p0 = blockIdx.x * 128;
    const int wr = wv >> 1, wc = wv & 1;

    f32x4 acc[4][4];
#pragma unroll
    for (int i = 0; i < 4; ++i)
#pragma unroll
        for (int j = 0; j < 4; ++j) acc[i][j] = (f32x4){0.f, 0.f, 0.f, 0.f};

    const size_t brow = (size_t)b * 1024 + p0 + wv * 32 + (lane >> 2);
    const _Float16* bsh = xh + brow * 512 + (lane & 3) * 8;
    const _Float16* bsl = xl + brow * 512 + (lane & 3) * 8;

    for (int kb = 0; kb < 16; ++kb) {
        const int k0 = kb * 32;
        F4 av[4];
#pragma unroll
        for (int j = 0; j < 4; ++j) {
            const int idx = j * 256 + t, row = idx >> 3, q = idx & 7;
            av[j].v = *(const float4*)&w[(size_t)(o0 + row) * 512 + k0 + q * 4];
        }
        __syncthreads();      // previous step's LDS reads complete
#pragma unroll
        for (int j = 0; j < 4; ++j) {
            const int idx = j * 256 + t, row = idx >> 3, q = idx & 7;
            H4 hh, hl;
#pragma unroll
            for (int i = 0; i < 4; ++i) {
                const float s = av[j].f[i] * 256.f;
                const _Float16 h = (_Float16)s;
                hh.h[i] = h;
                hl.h[i] = (_Float16)(s - (float)h);
            }
            *(uint2*)&Ah[row * 32 + q * 4] = hh.u;
            *(uint2*)&Al[row * 32 + q * 4] = hl.u;
        }
#pragma unroll
        for (int j = 0; j < 2; ++j) {
            gld16(bsh + (size_t)(j * 16) * 512 + k0, &Bh[(wv * 32 + j * 16) * 32]);
            gld16(bsl + (size_t)(j * 16) * 512 + k0, &Bl[(wv * 32 + j * 16) * 32]);
        }
        __syncthreads();
        f16x8 ah[4], al[4], bh[4], bl[4];
#pragma unroll
        for (int i = 0; i < 4; ++i) {
            const int ao = (wr * 64 + i * 16 + (lane & 15)) * 32 + (lane >> 4) * 8;
            const int bo = (wc * 64 + i * 16 + (lane & 15)) * 32 + (lane >> 4) * 8;
            ah[i] = *(f16x8*)&Ah[ao];
            al[i] = *(f16x8*)&Al[ao];
            bh[i] = *(f16x8*)&Bh[bo];
            bl[i] = *(f16x8*)&Bl[bo];
        }
#pragma unroll
        for (int mi = 0; mi < 4; ++mi)
#pragma unroll
            for (int nj = 0; nj < 4; ++nj) {
                acc[mi][nj] = __builtin_amdgcn_mfma_f32_16x16x32_f16(ah[mi], bh[nj], acc[mi][nj], 0, 0, 0);
                acc[mi][nj] = __builtin_amdgcn_mfma_f32_16x16x32_f16(ah[mi], bl[nj], acc[mi][nj], 0, 0, 0);
                acc[mi][nj] = __builtin_amdgcn_mfma_f32_16x16x32_f16(al[mi], bh[nj], acc[mi][nj], 0, 0, 0);
            }
    }
#pragma unroll
    for (int mi = 0; mi < 4; ++mi)
#pragma unroll
        for (int r = 0; r < 4; ++r) {
            const int o = o0 + wr * 64 + mi * 16 + (lane >> 4) * 4 + r;
            const float bs = bias[o];
#pragma unroll
            for (int nj = 0; nj < 4; ++nj) {
                const int p = p0 + wc * 64 + nj * 16 + (lane & 15);
                feat[((size_t)b * 512 + o) * HW + p] = acc[mi][nj][r] * (1.f / 65536.f) + bs;
            }
        }
}

// ---------------- k_value: 1-term MFMA GEMM, fp16 out ----------------
__global__ __launch_bounds__(256) void k_value(
    const float* __restrict__ w, const float* __restrict__ bias,
    const _Float16* __restrict__ xh, _Float16* __restrict__ value_h)
{
    __shared__ _Float16 Ah[128 * 32], Bh[128 * 32];
    const int t = threadIdx.x, lane = t & 63, wv = t >> 6;
    const int b = blockIdx.z, o0 = blockIdx.y * 128, p0 = blockIdx.x * 128;
    const int wr = wv >> 1, wc = wv & 1;

    f32x4 acc[4][4];
#pragma unroll
    for (int i = 0; i < 4; ++i)
#pragma unroll
        for (int j = 0; j < 4; ++j) acc[i][j] = (f32x4){0.f, 0.f, 0.f, 0.f};

    const _Float16* bsh = xh + ((size_t)b * 1024 + p0 + wv * 32 + (lane >> 2)) * 512 + (lane & 3) * 8;

    for (int kb = 0; kb < 16; ++kb) {
        const int k0 = kb * 32;
        F4 av[4];
#pragma unroll
        for (int j = 0; j < 4; ++j) {
            const int idx = j * 256 + t, row = idx >> 3, q = idx & 7;
            av[j].v = *(const float4*)&w[(size_t)(o0 + row) * 512 + k0 + q * 4];
        }
        __syncthreads();
#pragma unroll
        for (int j = 0; j < 4; ++j) {
            const int idx = j * 256 + t, row = idx >> 3, q = idx & 7;
            H4 hh;
#pragma unroll
            for (int i = 0; i < 4; ++i) hh.h[i] = (_Float16)(av[j].f[i] * 256.f);
            *(uint2*)&Ah[row * 32 + q * 4] = hh.u;
        }
#pragma unroll
        for (int j = 0; j < 2; ++j)
            gld16(bsh + (size_t)(j * 16) * 512 + k0, &Bh[(wv * 32 + j * 16) * 32]);
        __syncthreads();
        f16x8 ah[4], bh[4];
#pragma unroll
        for (int i = 0; i < 4; ++i) {
            ah[i] = *(f16x8*)&Ah[(wr * 64 + i * 16 + (lane & 15)) * 32 + (lane >> 4) * 8];
            bh[i] = *(f16x8*)&Bh[(wc * 64 + i * 16 + (lane & 15)) * 32 + (lane >> 4) * 8];
        }
#pragma unroll
        for (int mi = 0; mi < 4; ++mi)
#pragma unroll
            for (int nj = 0; nj < 4; ++nj)
                acc[mi][nj] = __builtin_amdgcn_mfma_f32_16x16x32_f16(ah[mi], bh[nj], acc[mi][nj], 0, 0, 0);
    }
#pragma unroll
    for (int mi = 0; mi < 4; ++mi)
#pragma unroll
        for (int r = 0; r < 4; ++r) {
            const int o = o0 + wr * 64 + mi * 16 + (lane >> 4) * 4 + r;
            const float bs = bias[o];
#pragma unroll
            for (int nj = 0; nj < 4; ++nj) {
                const int p = p0 + wc * 64 + nj * 16 + (lane & 15);
                value_h[((size_t)b * 512 + o) * HW + p] =
                    (_Float16)(acc[mi][nj][r] * (1.f / 65536.f) + bs);
            }
        }
}

// ---------------- k_cluster ----------------
__global__ __launch_bounds__(256) void k_cluster(
    const float* __restrict__ feat,
    const _Float16* __restrict__ value_h,
    const float* __restrict__ alpha_p, const float* __restrict__ beta_p,
    _Float16* __restrict__ outpT,          // [b][p][512]
    float* __restrict__ part)
{
    __shared__ float buf[256 * 64];
    __shared__ float cbuf[4 * 64];
    __shared__ float cinv[4];
    __shared__ int   sidx[256];
    __shared__ float red[8];
    __shared__ float gsc[16];

    const int t = threadIdx.x;
    const int lane = t & 63, wave = t >> 6;
    const int bp = blockIdx.x;
    const int f2 = bp & 1, f1 = (bp >> 1) & 1, head = (bp >> 2) & 7, b = bp >> 5;
    const size_t base = ((size_t)b * 512 + head * 64) * HW + f1 * 512 + f2 * 16;

    // ---- stage feat (fp32 float4) ----
#pragma unroll
    for (int i = 0; i < 16; ++i) {
        const int q = i * 256 + t;
        const int c = q >> 6;
        const int n0 = (q & 63) * 4;
        const float4 v = *(const float4*)&feat[base + (size_t)c * HW + (n0 >> 4) * 32 + (n0 & 15)];
        buf[sw_idx(n0 + 0, c)] = v.x;
        buf[sw_idx(n0 + 1, c)] = v.y;
        buf[sw_idx(n0 + 2, c)] = v.z;
        buf[sw_idx(n0 + 3, c)] = v.w;
    }
    __syncthreads();

    const int m = t >> 6, cc = t & 63;
    const int pi = m >> 1, pj = m & 1;
    float cs = 0.f;
#pragma unroll
    for (int wp = 0; wp < 8; ++wp)
#pragma unroll
        for (int hp = 0; hp < 8; ++hp)
            cs += buf[sw_idx((pi * 8 + wp) * 16 + pj * 8 + hp, cc)];
    const float cv = cs * (1.f / 64.f);
    cbuf[m * 64 + cc] = cv;
    float ssc = cv * cv;
#pragma unroll
    for (int off = 32; off > 0; off >>= 1) ssc += __shfl_xor(ssc, off);
    if (lane == 0) cinv[m] = 1.f / fmaxf(sqrtf(ssc), 1e-12f);
    __syncthreads();

    if (t < 16) {
        const int gm = t >> 2, gk = t & 3;
        float g = 0.f;
        for (int c = 0; c < 64; ++c) g += cbuf[gm * 64 + c] * cbuf[gk * 64 + c];
        g *= cinv[gm] * cinv[gk];
        const float d = g - (gm == gk ? 1.f : 0.f);
        gsc[t] = d * d;
    }

    const float alpha = alpha_p[0], beta = beta_p[0];
    const int n = t;
    float ssf = 0.f, dot0 = 0.f, dot1 = 0.f, dot2 = 0.f, dot3 = 0.f;
    for (int c = 0; c < 64; ++c) {
        const float fv = buf[sw_idx(n, c)];
        ssf += fv * fv;
        dot0 = fmaf(fv, cbuf[0 * 64 + c], dot0);
        dot1 = fmaf(fv, cbuf[1 * 64 + c], dot1);
        dot2 = fmaf(fv, cbuf[2 * 64 + c], dot2);
        dot3 = fmaf(fv, cbuf[3 * 64 + c], dot3);
    }
    const float invf = 1.f / fmaxf(sqrtf(ssf), 1e-12f);
    float simv[4];
    simv[0] = dot0 * invf * cinv[0];
    simv[1] = dot1 * invf * cinv[1];
    simv[2] = dot2 * invf * cinv[2];
    simv[3] = dot3 * invf * cinv[3];
#pragma unroll
    for (int mm = 0; mm < 4; ++mm)
        simv[mm] = 1.f / (1.f + expf(-(beta + alpha * simv[mm])));
    float best = simv[0], second = -1.f;
    int idx = 0;
#pragma unroll
    for (int mm = 1; mm < 4; ++mm) {
        if (simv[mm] > best) { second = best; best = simv[mm]; idx = mm; }
        else second = fmaxf(second, simv[mm]);
    }
    sidx[n] = idx;

    float bsum = best, s2sum = second;
#pragma unroll
    for (int off = 32; off > 0; off >>= 1) {
        bsum += __shfl_xor(bsum, off);
        s2sum += __shfl_xor(s2sum, off);
    }
    if (lane == 0) { red[wave] = bsum; red[4 + wave] = s2sum; }
    __syncthreads();
    if (t == 0) {
        part[bp]        = gsc[0] + gsc[1] + gsc[2] + gsc[3] + gsc[4] + gsc[5] + gsc[6] + gsc[7]
                        + gsc[8] + gsc[9] + gsc[10] + gsc[11] + gsc[12] + gsc[13] + gsc[14] + gsc[15];
        part[1024 + bp] = red[0] + red[1] + red[2] + red[3];
        part[2048 + bp] = red[4] + red[5] + red[6] + red[7];
    }

    // ---- stage value (fp16 x4) over buf ----
#pragma unroll
    for (int i = 0; i < 16; ++i) {
        const int q = i * 256 + t;
        const int c = q >> 6;
        const int n0 = (q & 63) * 4;
        const uint2 vv = *(const uint2*)&value_h[base + (size_t)c * HW + (n0 >> 4) * 32 + (n0 & 15)];
        const _Float16* hv = (const _Float16*)&vv;
        buf[sw_idx(n0 + 0, c)] = (float)hv[0];
        buf[sw_idx(n0 + 1, c)] = (float)hv[1];
        buf[sw_idx(n0 + 2, c)] = (float)hv[2];
        buf[sw_idx(n0 + 3, c)] = (float)hv[3];
    }
    __syncthreads();

    float vcs = 0.f;
#pragma unroll
    for (int wp = 0; wp < 8; ++wp)
#pragma unroll
        for (int hp = 0; hp < 8; ++hp)
            vcs += buf[sw_idx((pi * 8 + wp) * 16 + pj * 8 + hp, cc)];
    const float vc = vcs * (1.f / 64.f);
    float agg = 0.f;
    int cnt = 0;
    for (int nn = 0; nn < 256; ++nn) {
        if (sidx[nn] == m) { agg += buf[sw_idx(nn, cc)]; ++cnt; }
    }
    cbuf[m * 64 + cc] = (agg + vc) / (float)(cnt + 1);
    __syncthreads();

    // ---- outp -> outpT fp16 [b][p][head*64+c] ----
    const int p = (f1 * 16 + (n >> 4)) * 32 + f2 * 16 + (n & 15);
    _Float16* op = outpT + ((size_t)b * 1024 + p) * 512 + head * 64;
#pragma unroll
    for (int c4 = 0; c4 < 16; ++c4) {
        H4 o4;
#pragma unroll
        for (int i = 0; i < 4; ++i)
            o4.h[i] = (_Float16)(best * cbuf[idx * 64 + c4 * 4 + i]);
        *(uint2*)&op[c4 * 4] = o4.u;
    }
}

// ---------------- k_proj: 1-term MFMA GEMM + loss finalize ----------------
__global__ __launch_bounds__(256) void k_proj(
    const float* __restrict__ w, const float* __restrict__ bias,
    const _Float16* __restrict__ outpT,
    const float* __restrict__ part,
    float* __restrict__ dout)
{
    __shared__ _Float16 Ah[128 * 32], Bh[128 * 32];
    __shared__ float fin[12];
    const int t = threadIdx.x, lane = t & 63, wv = t >> 6;

    if (blockIdx.x == 0 && blockIdx.y == 0 && blockIdx.z == 0) {
        float so = part[t] + part[t + 256] + part[t + 512] + part[t + 768];
        float sc = part[1024 + t] + part[1280 + t] + part[1536 + t] + part[1792 + t];
        float sp = part[2048 + t] + part[2304 + t] + part[2560 + t] + part[2816 + t];
#pragma unroll
        for (int off = 32; off > 0; off >>= 1) {
            so += __shfl_xor(so, off);
            sc += __shfl_xor(sc, off);
            sp += __shfl_xor(sp, off);
        }
        if (lane == 0) { fin[wv] = so; fin[4 + wv] = sc; fin[8 + wv] = sp; }
        __syncthreads();
        if (t == 0) {
            dout[16777216]     = (fin[0] + fin[1] + fin[2] + fin[3]) / 16384.f;
            dout[16777216 + 1] = -(fin[4] + fin[5] + fin[6] + fin[7]) / 262144.f;
            dout[16777216 + 2] = (fin[8] + fin[9] + fin[10] + fin[11]) / 262144.f;
        }
        __syncthreads();
    }

    const int b = blockIdx.z, o0 = blockIdx.y * 128, p0 = blockIdx.x * 128;
    const int wr = wv >> 1, wc = wv & 1;

    f32x4 acc[4][4];
#pragma unroll
    for (int i = 0; i < 4; ++i)
#pragma unroll
        for (int j = 0; j < 4; ++j) acc[i][j] = (f32x4){0.f, 0.f, 0.f, 0.f};

    const _Float16* bsh = outpT + ((size_t)b * 1024 + p0 + wv * 32 + (lane >> 2)) * 512 + (lane & 3) * 8;

    for (int kb = 0; kb < 16; ++kb) {
        const int k0 = kb * 32;
        F4 av[4];
#pragma unroll
        for (int j = 0; j < 4; ++j) {
            const int idx = j * 256 + t, row = idx >> 3, q = idx & 7;
            av[j].v = *(const float4*)&w[(size_t)(o0 + row) * 512 + k0 + q * 4];
        }
        __syncthreads();
#pragma unroll
        for (int j = 0; j < 4; ++j) {
            const int idx = j * 256 + t, row = idx >> 3, q = idx & 7;
            H4 hh;
#pragma unroll
            for (int i = 0; i < 4; ++i) hh.h[i] = (_Float16)(av[j].f[i] * 256.f);
            *(uint2*)&Ah[row * 32 + q * 4] = hh.u;
        }
#pragma unroll
        for (int j = 0; j < 2; ++j)
            gld16(bsh + (size_t)(j * 16) * 512 + k0, &Bh[(wv * 32 + j * 16) * 32]);
        __syncthreads();
        f16x8 ah[4], bh[4];
#pragma unroll
        for (int i = 0; i < 4; ++i) {
            ah[i] = *(f16x8*)&Ah[(wr * 64 + i * 16 + (lane & 15)) * 32 + (lane >> 4) * 8];
            bh[i] = *(f16x8*)&Bh[(wc * 64 + i * 16 + (lane & 15)) * 32 + (lane >> 4) * 8];
        }
#pragma unroll
        for (int mi = 0; mi < 4; ++mi)
#pragma unroll
            for (int nj = 0; nj < 4; ++nj)
                acc[mi][nj] = __builtin_amdgcn_mfma_f32_16x16x32_f16(ah[mi], bh[nj], acc[mi][nj], 0, 0, 0);
    }
#pragma unroll
    for (int mi = 0; mi < 4; ++mi)
#pragma unroll
        for (int r = 0; r < 4; ++r) {
            const int o = o0 + wr * 64 + mi * 16 + (lane >> 4) * 4 + r;
            const float bs = bias[o];
#pragma unroll
            for (int nj = 0; nj < 4; ++nj) {
                const int p = p0 + wc * 64 + nj * 16 + (lane & 15);
                dout[((size_t)b * 512 + o) * HW + p] = acc[mi][nj][r] * (1.f / 256.f) + bs;
            }
        }
}

extern "C" void kernel_launch(void* const* d_in, const int* in_sizes, int n_in,
                              void* d_out, int out_size, void* d_ws, size_t ws_size,
                              hipStream_t stream)
{
    const float* x   = (const float*)d_in[0];
    const float* f_w = (const float*)d_in[1];
    const float* f_b = (const float*)d_in[2];
    const float* v_w = (const float*)d_in[3];
    const float* v_b = (const float*)d_in[4];
    const float* p_w = (const float*)d_in[5];
    const float* p_b = (const float*)d_in[6];
    const float* s_a = (const float*)d_in[7];
    const float* s_b = (const float*)d_in[8];
    float* out = (float*)d_out;

    char* ws = (char*)d_ws;
    float*     feat    = (float*)ws;                              // [0, 64 MB)
    _Float16*  xh      = (_Float16*)(ws + (size_t)64 * 1024 * 1024);   // [64, 96)
    _Float16*  xl      = (_Float16*)(ws + (size_t)96 * 1024 * 1024);   // [96, 128)
    _Float16*  outpT   = xh;                                      // reuse after k_value
    _Float16*  value_h = xl;                                      // reuse after k_feat
    float*     part    = (float*)(ws + (size_t)128 * 1024 * 1024);     // 12 KB

    k_xsplit<<<dim3(16, 8, 32), 256, 0, stream>>>(x, xh, xl);
    k_feat  <<<dim3(8, 4, 32), 256, 0, stream>>>(f_w, f_b, xh, xl, feat);
    k_value <<<dim3(8, 4, 32), 256, 0, stream>>>(v_w, v_b, xh, value_h);
    k_cluster<<<dim3(1024), 256, 0, stream>>>(feat, value_h, s_a, s_b, outpT, part);
    k_proj  <<<dim3(8, 4, 32), 256, 0, stream>>>(p_w, p_b, outpT, part, out);
}

// Round 3
// 231.606 us; speedup vs baseline: 3.0967x; 1.2708x over previous
//
#include <hip/hip_runtime.h>

// ---------------------------------------------------------------------------
// Round 3: k_cluster rewrite (streaming centers, fp16 value tile, parallel agg,
// coalesced outpT in [b][8][1024][64] layout) + k_proj B-staging for new layout.
// k_xsplit / k_feat / k_value unchanged from round 2.
// ws: [0,64M) feat fp32 | [64M,96M) xh -> outpT | [96M,128M) xl -> value_h | +12KB part
// ---------------------------------------------------------------------------

#define HW 1024

typedef _Float16 f16x8 __attribute__((ext_vector_type(8)));
typedef float f32x4 __attribute__((ext_vector_type(4)));

union H4 { uint2 u; _Float16 h[4]; };
union H8 { uint4 u; _Float16 h[8]; };
union H2 { unsigned int u; _Float16 h[2]; };
union F4 { float4 v; float f[4]; };

__device__ __forceinline__ void gld16(const _Float16* g, _Float16* l) {
    __builtin_amdgcn_global_load_lds(
        (const __attribute__((address_space(1))) void*)g,
        (__attribute__((address_space(3))) void*)l, 16, 0, 0);
}

// ---------------- k_xsplit: transpose + fp16 split (unchanged) ----------------
__global__ __launch_bounds__(256) void k_xsplit(
    const float* __restrict__ x,
    _Float16* __restrict__ xh, _Float16* __restrict__ xl)
{
    __shared__ float tile[64][65];
    const int t = threadIdx.x;
    const int b = blockIdx.z;
    const int k0 = blockIdx.y * 64;
    const int n0 = blockIdx.x * 64;
    const float* Xb = x + (size_t)b * (512 * HW);

#pragma unroll
    for (int j = 0; j < 16; ++j) {
        const int k = j * 4 + (t >> 6);
        const int n = t & 63;
        tile[k][n] = Xb[(size_t)(k0 + k) * HW + n0 + n];
    }
    __syncthreads();
#pragma unroll
    for (int j = 0; j < 8; ++j) {
        const int n = j * 8 + (t >> 5);
        const int kp = t & 31;
        const float s0 = tile[kp * 2][n] * 256.f;
        const float s1 = tile[kp * 2 + 1][n] * 256.f;
        H2 hh, hl;
        hh.h[0] = (_Float16)s0;
        hh.h[1] = (_Float16)s1;
        hl.h[0] = (_Float16)(s0 - (float)hh.h[0]);
        hl.h[1] = (_Float16)(s1 - (float)hh.h[1]);
        const size_t o = ((size_t)b * 1024 + n0 + n) * 512 + k0 + kp * 2;
        *(unsigned int*)&xh[o] = hh.u;
        *(unsigned int*)&xl[o] = hl.u;
    }
}

// ---------------- k_feat: 3-term split MFMA GEMM (unchanged) ----------------
__global__ __launch_bounds__(256) void k_feat(
    const float* __restrict__ w, const float* __restrict__ bias,
    const _Float16* __restrict__ xh, const _Float16* __restrict__ xl,
    float* __restrict__ feat)
{
    __shared__ _Float16 Ah[128 * 32], Al[128 * 32], Bh[128 * 32], Bl[128 * 32];
    const int t = threadIdx.x, lane = t & 63, wv = t >> 6;
    const int b = blockIdx.z, o0 = blockIdx.y * 128, p0 = blockIdx.x * 128;
    const int wr = wv >> 1, wc = wv & 1;

    f32x4 acc[4][4];
#pragma unroll
    for (int i = 0; i < 4; ++i)
#pragma unroll
        for (int j = 0; j < 4; ++j) acc[i][j] = (f32x4){0.f, 0.f, 0.f, 0.f};

    const size_t brow = (size_t)b * 1024 + p0 + wv * 32 + (lane >> 2);
    const _Float16* bsh = xh + brow * 512 + (lane & 3) * 8;
    const _Float16* bsl = xl + brow * 512 + (lane & 3) * 8;

    for (int kb = 0; kb < 16; ++kb) {
        const int k0 = kb * 32;
        F4 av[4];
#pragma unroll
        for (int j = 0; j < 4; ++j) {
            const int idx = j * 256 + t, row = idx >> 3, q = idx & 7;
            av[j].v = *(const float4*)&w[(size_t)(o0 + row) * 512 + k0 + q * 4];
        }
        __syncthreads();
#pragma unroll
        for (int j = 0; j < 4; ++j) {
            const int idx = j * 256 + t, row = idx >> 3, q = idx & 7;
            H4 hh, hl;
#pragma unroll
            for (int i = 0; i < 4; ++i) {
                const float s = av[j].f[i] * 256.f;
                const _Float16 h = (_Float16)s;
                hh.h[i] = h;
                hl.h[i] = (_Float16)(s - (float)h);
            }
            *(uint2*)&Ah[row * 32 + q * 4] = hh.u;
            *(uint2*)&Al[row * 32 + q * 4] = hl.u;
        }
#pragma unroll
        for (int j = 0; j < 2; ++j) {
            gld16(bsh + (size_t)(j * 16) * 512 + k0, &Bh[(wv * 32 + j * 16) * 32]);
            gld16(bsl + (size_t)(j * 16) * 512 + k0, &Bl[(wv * 32 + j * 16) * 32]);
        }
        __syncthreads();
        f16x8 ah[4], al[4], bh[4], bl[4];
#pragma unroll
        for (int i = 0; i < 4; ++i) {
            const int ao = (wr * 64 + i * 16 + (lane & 15)) * 32 + (lane >> 4) * 8;
            const int bo = (wc * 64 + i * 16 + (lane & 15)) * 32 + (lane >> 4) * 8;
            ah[i] = *(f16x8*)&Ah[ao];
            al[i] = *(f16x8*)&Al[ao];
            bh[i] = *(f16x8*)&Bh[bo];
            bl[i] = *(f16x8*)&Bl[bo];
        }
#pragma unroll
        for (int mi = 0; mi < 4; ++mi)
#pragma unroll
            for (int nj = 0; nj < 4; ++nj) {
                acc[mi][nj] = __builtin_amdgcn_mfma_f32_16x16x32_f16(ah[mi], bh[nj], acc[mi][nj], 0, 0, 0);
                acc[mi][nj] = __builtin_amdgcn_mfma_f32_16x16x32_f16(ah[mi], bl[nj], acc[mi][nj], 0, 0, 0);
                acc[mi][nj] = __builtin_amdgcn_mfma_f32_16x16x32_f16(al[mi], bh[nj], acc[mi][nj], 0, 0, 0);
            }
    }
#pragma unroll
    for (int mi = 0; mi < 4; ++mi)
#pragma unroll
        for (int r = 0; r < 4; ++r) {
            const int o = o0 + wr * 64 + mi * 16 + (lane >> 4) * 4 + r;
            const float bs = bias[o];
#pragma unroll
            for (int nj = 0; nj < 4; ++nj) {
                const int p = p0 + wc * 64 + nj * 16 + (lane & 15);
                feat[((size_t)b * 512 + o) * HW + p] = acc[mi][nj][r] * (1.f / 65536.f) + bs;
            }
        }
}

// ---------------- k_value: 1-term MFMA GEMM, fp16 out (unchanged) ----------------
__global__ __launch_bounds__(256) void k_value(
    const float* __restrict__ w, const float* __restrict__ bias,
    const _Float16* __restrict__ xh, _Float16* __restrict__ value_h)
{
    __shared__ _Float16 Ah[128 * 32], Bh[128 * 32];
    const int t = threadIdx.x, lane = t & 63, wv = t >> 6;
    const int b = blockIdx.z, o0 = blockIdx.y * 128, p0 = blockIdx.x * 128;
    const int wr = wv >> 1, wc = wv & 1;

    f32x4 acc[4][4];
#pragma unroll
    for (int i = 0; i < 4; ++i)
#pragma unroll
        for (int j = 0; j < 4; ++j) acc[i][j] = (f32x4){0.f, 0.f, 0.f, 0.f};

    const _Float16* bsh = xh + ((size_t)b * 1024 + p0 + wv * 32 + (lane >> 2)) * 512 + (lane & 3) * 8;

    for (int kb = 0; kb < 16; ++kb) {
        const int k0 = kb * 32;
        F4 av[4];
#pragma unroll
        for (int j = 0; j < 4; ++j) {
            const int idx = j * 256 + t, row = idx >> 3, q = idx & 7;
            av[j].v = *(const float4*)&w[(size_t)(o0 + row) * 512 + k0 + q * 4];
        }
        __syncthreads();
#pragma unroll
        for (int j = 0; j < 4; ++j) {
            const int idx = j * 256 + t, row = idx >> 3, q = idx & 7;
            H4 hh;
#pragma unroll
            for (int i = 0; i < 4; ++i) hh.h[i] = (_Float16)(av[j].f[i] * 256.f);
            *(uint2*)&Ah[row * 32 + q * 4] = hh.u;
        }
#pragma unroll
        for (int j = 0; j < 2; ++j)
            gld16(bsh + (size_t)(j * 16) * 512 + k0, &Bh[(wv * 32 + j * 16) * 32]);
        __syncthreads();
        f16x8 ah[4], bh[4];
#pragma unroll
        for (int i = 0; i < 4; ++i) {
            ah[i] = *(f16x8*)&Ah[(wr * 64 + i * 16 + (lane & 15)) * 32 + (lane >> 4) * 8];
            bh[i] = *(f16x8*)&Bh[(wc * 64 + i * 16 + (lane & 15)) * 32 + (lane >> 4) * 8];
        }
#pragma unroll
        for (int mi = 0; mi < 4; ++mi)
#pragma unroll
            for (int nj = 0; nj < 4; ++nj)
                acc[mi][nj] = __builtin_amdgcn_mfma_f32_16x16x32_f16(ah[mi], bh[nj], acc[mi][nj], 0, 0, 0);
    }
#pragma unroll
    for (int mi = 0; mi < 4; ++mi)
#pragma unroll
        for (int r = 0; r < 4; ++r) {
            const int o = o0 + wr * 64 + mi * 16 + (lane >> 4) * 4 + r;
            const float bs = bias[o];
#pragma unroll
            for (int nj = 0; nj < 4; ++nj) {
                const int p = p0 + wc * 64 + nj * 16 + (lane & 15);
                value_h[((size_t)b * 512 + o) * HW + p] =
                    (_Float16)(acc[mi][nj][r] * (1.f / 65536.f) + bs);
            }
        }
}

// ---------------- k_cluster: streaming rewrite ----------------
// one block per folded batch; 256 threads.
// LDS ~41 KB -> 3 blocks/CU (was 68 KB -> 2).
__global__ __launch_bounds__(256) void k_cluster(
    const float* __restrict__ feat,
    const _Float16* __restrict__ value_h,
    const float* __restrict__ alpha_p, const float* __restrict__ beta_p,
    _Float16* __restrict__ outpT,          // [b][8][1024][64] fp16
    float* __restrict__ part)
{
    __shared__ _Float16 vbuf[256 * 64];    // 32 KB swizzled value tile
    __shared__ float cnl[4][64];           // centers -> normalized centers
    __shared__ float vcl[4][64];           // value centers
    __shared__ float obuf[4][68];          // cluster outputs (padded)
    __shared__ int   sidx[256];
    __shared__ float sbest[256];
    __shared__ float scrt[4][4][64];       // per-wave agg partials
    __shared__ int   cntw[4][4];
    __shared__ float cinv[4];
    __shared__ float red[8];
    __shared__ float gsc[16];

    const int t = threadIdx.x, lane = t & 63, wv = t >> 6;
    const int bp = blockIdx.x;
    const int f2 = bp & 1, f1 = (bp >> 1) & 1, head = (bp >> 2) & 7, b = bp >> 5;
    const size_t base = ((size_t)b * 512 + head * 64) * HW + f1 * 512 + f2 * 16;

    // ---- phase A: feat centers by streaming + shfl groups ----
    // lane l loads float4 = points n=4l..4l+3 (all share center m):
    //   m = ((l>>5)<<1) | ((l>>1)&1); reduce over lane bits {0,2,3,4}
    const int sp4 = (lane >> 2) * 32 + (lane & 3) * 4;
    const int mA = ((lane >> 5) << 1) | ((lane >> 1) & 1);
#pragma unroll
    for (int i = 0; i < 16; ++i) {
        const int c = wv * 16 + i;
        F4 v;
        v.v = *(const float4*)&feat[base + (size_t)c * HW + sp4];
        float s = (v.f[0] + v.f[1]) + (v.f[2] + v.f[3]);
        s += __shfl_xor(s, 1);
        s += __shfl_xor(s, 4);
        s += __shfl_xor(s, 8);
        s += __shfl_xor(s, 16);
        if ((lane & 29) == 0) cnl[mA][c] = s * (1.f / 64.f);   // lanes 0,2,32,34
    }
    __syncthreads();

    // ---- center norms, normalize in place ----
    const int m = t >> 6, cc = lane;
    {
        const float fc = cnl[m][cc];
        float ss = fc * fc;
#pragma unroll
        for (int off = 32; off > 0; off >>= 1) ss += __shfl_xor(ss, off);
        if (lane == 0) cinv[m] = 1.f / fmaxf(sqrtf(ss), 1e-12f);
        __syncthreads();
        cnl[m][cc] = fc * cinv[m];
    }
    __syncthreads();

    // ---- G / L_Orth partial (normalized centers) ----
    if (t < 16) {
        const int gm = t >> 2, gk = t & 3;
        float g = 0.f;
        for (int c = 0; c < 64; ++c) g += cnl[gm][c] * cnl[gk][c];
        const float d = g - (gm == gk ? 1.f : 0.f);
        gsc[t] = d * d;
    }

    // ---- phase B: per-point dots (stream feat again, L2-hot) ----
    const float alpha = alpha_p[0], beta = beta_p[0];
    const int n = t;
    const int spn = (n >> 4) * 32 + (n & 15);
    float ssf = 0.f, d0 = 0.f, d1 = 0.f, d2 = 0.f, d3 = 0.f;
#pragma unroll
    for (int c4 = 0; c4 < 16; ++c4) {
        float fv[4];
#pragma unroll
        for (int j = 0; j < 4; ++j)
            fv[j] = feat[base + (size_t)(c4 * 4 + j) * HW + spn];
        const float4 c0 = *(const float4*)&cnl[0][c4 * 4];
        const float4 c1 = *(const float4*)&cnl[1][c4 * 4];
        const float4 c2 = *(const float4*)&cnl[2][c4 * 4];
        const float4 c3 = *(const float4*)&cnl[3][c4 * 4];
        ssf += fv[0]*fv[0] + fv[1]*fv[1] + fv[2]*fv[2] + fv[3]*fv[3];
        d0 += fv[0]*c0.x + fv[1]*c0.y + fv[2]*c0.z + fv[3]*c0.w;
        d1 += fv[0]*c1.x + fv[1]*c1.y + fv[2]*c1.z + fv[3]*c1.w;
        d2 += fv[0]*c2.x + fv[1]*c2.y + fv[2]*c2.z + fv[3]*c2.w;
        d3 += fv[0]*c3.x + fv[1]*c3.y + fv[2]*c3.z + fv[3]*c3.w;
    }
    const float invf = 1.f / fmaxf(sqrtf(ssf), 1e-12f);
    float simv[4];
    simv[0] = d0 * invf;
    simv[1] = d1 * invf;
    simv[2] = d2 * invf;
    simv[3] = d3 * invf;
#pragma unroll
    for (int mm = 0; mm < 4; ++mm)
        simv[mm] = 1.f / (1.f + expf(-(beta + alpha * simv[mm])));
    float best = simv[0], second = -1.f;
    int idx = 0;
#pragma unroll
    for (int mm = 1; mm < 4; ++mm) {
        if (simv[mm] > best) { second = best; best = simv[mm]; idx = mm; }
        else second = fmaxf(second, simv[mm]);
    }
    sidx[n] = idx;
    sbest[n] = best;

    // ---- phase D: stage value tile (fp16, swizzled) ----
    // half-word index: v_idx(n,c) = n*64 + (c ^ (((n>>2)&31)<<1))
#pragma unroll
    for (int i = 0; i < 16; ++i) {
        const int q = i * 256 + t;
        const int c = q >> 6;
        const int n0 = (q & 63) * 4;
        H4 v;
        v.u = *(const uint2*)&value_h[base + (size_t)c * HW + (n0 >> 4) * 32 + (n0 & 15)];
        const int swz = ((n0 >> 2) & 31) << 1;
#pragma unroll
        for (int j = 0; j < 4; ++j)
            vbuf[(n0 + j) * 64 + (c ^ swz)] = v.h[j];
    }

    // ---- loss partial reduce ----
    float bsum = best, s2sum = second;
#pragma unroll
    for (int off = 32; off > 0; off >>= 1) {
        bsum += __shfl_xor(bsum, off);
        s2sum += __shfl_xor(s2sum, off);
    }
    if (lane == 0) { red[wv] = bsum; red[4 + wv] = s2sum; }
    __syncthreads();   // covers gsc, red, sidx, sbest, vbuf
    if (t == 0) {
        part[bp]        = gsc[0] + gsc[1] + gsc[2] + gsc[3] + gsc[4] + gsc[5] + gsc[6] + gsc[7]
                        + gsc[8] + gsc[9] + gsc[10] + gsc[11] + gsc[12] + gsc[13] + gsc[14] + gsc[15];
        part[1024 + bp] = red[0] + red[1] + red[2] + red[3];
        part[2048 + bp] = red[4] + red[5] + red[6] + red[7];
    }

    // ---- value centers from vbuf: thread (m, cc) ----
    {
        const int pi = m >> 1, pj = m & 1;
        float vcs = 0.f;
#pragma unroll
        for (int wp = 0; wp < 8; ++wp)
#pragma unroll
            for (int hp = 0; hp < 8; ++hp) {
                const int nn = (pi * 8 + wp) * 16 + pj * 8 + hp;
                vcs += (float)vbuf[nn * 64 + (cc ^ (((nn >> 2) & 31) << 1))];
            }
        vcl[m][cc] = vcs * (1.f / 64.f);
    }

    // ---- phase E: parallel agg scan (wave wv covers 64 points) ----
    {
        float ag0 = 0.f, ag1 = 0.f, ag2 = 0.f, ag3 = 0.f;
        int c0i = 0, c1i = 0, c2i = 0, c3i = 0;
        for (int j = 0; j < 64; ++j) {
            const int nn = wv * 64 + j;
            const int id = sidx[nn];
            const float v = (float)vbuf[nn * 64 + (cc ^ (((nn >> 2) & 31) << 1))];
            ag0 += (id == 0) ? v : 0.f;  c0i += (id == 0);
            ag1 += (id == 1) ? v : 0.f;  c1i += (id == 1);
            ag2 += (id == 2) ? v : 0.f;  c2i += (id == 2);
            ag3 += (id == 3) ? v : 0.f;  c3i += (id == 3);
        }
        scrt[wv][0][cc] = ag0;
        scrt[wv][1][cc] = ag1;
        scrt[wv][2][cc] = ag2;
        scrt[wv][3][cc] = ag3;
        if (lane == 0) {
            cntw[wv][0] = c0i; cntw[wv][1] = c1i;
            cntw[wv][2] = c2i; cntw[wv][3] = c3i;
        }
    }
    __syncthreads();

    // ---- cluster outputs ----
    {
        const float a = scrt[0][m][cc] + scrt[1][m][cc] + scrt[2][m][cc] + scrt[3][m][cc];
        const int c = cntw[0][m] + cntw[1][m] + cntw[2][m] + cntw[3][m];
        obuf[m][cc] = (a + vcl[m][cc]) / (float)(c + 1);
    }
    __syncthreads();

    // ---- phase F: coalesced outpT write (4 lanes per point, 2KB/wave-store) ----
    const int cch = (t & 3) * 16;
#pragma unroll
    for (int r = 0; r < 4; ++r) {
        const int nn = r * 64 + (t >> 2);
        const int id = sidx[nn];
        const float bs = sbest[nn];
        const int p = (f1 * 16 + (nn >> 4)) * 32 + f2 * 16 + (nn & 15);
        _Float16* dst = outpT + (((size_t)b * 8 + head) * 1024 + p) * 64 + cch;
        const float4 oa = *(const float4*)&obuf[id][cch];
        const float4 ob = *(const float4*)&obuf[id][cch + 4];
        const float4 oc = *(const float4*)&obuf[id][cch + 8];
        const float4 od = *(const float4*)&obuf[id][cch + 12];
        H8 w0, w1;
        w0.h[0] = (_Float16)(bs * oa.x); w0.h[1] = (_Float16)(bs * oa.y);
        w0.h[2] = (_Float16)(bs * oa.z); w0.h[3] = (_Float16)(bs * oa.w);
        w0.h[4] = (_Float16)(bs * ob.x); w0.h[5] = (_Float16)(bs * ob.y);
        w0.h[6] = (_Float16)(bs * ob.z); w0.h[7] = (_Float16)(bs * ob.w);
        w1.h[0] = (_Float16)(bs * oc.x); w1.h[1] = (_Float16)(bs * oc.y);
        w1.h[2] = (_Float16)(bs * oc.z); w1.h[3] = (_Float16)(bs * oc.w);
        w1.h[4] = (_Float16)(bs * od.x); w1.h[5] = (_Float16)(bs * od.y);
        w1.h[6] = (_Float16)(bs * od.z); w1.h[7] = (_Float16)(bs * od.w);
        *(uint4*)dst = w0.u;
        *(uint4*)(dst + 8) = w1.u;
    }
}

// ---------------- k_proj: MFMA GEMM over outpT[b][8][1024][64] + loss finalize ----------------
__global__ __launch_bounds__(256) void k_proj(
    const float* __restrict__ w, const float* __restrict__ bias,
    const _Float16* __restrict__ outpT,
    const float* __restrict__ part,
    float* __restrict__ dout)
{
    __shared__ _Float16 Ah[128 * 32], Bh[128 * 32];
    __shared__ float fin[12];
    const int t = threadIdx.x, lane = t & 63, wv = t >> 6;

    if (blockIdx.x == 0 && blockIdx.y == 0 && blockIdx.z == 0) {
        float so = part[t] + part[t + 256] + part[t + 512] + part[t + 768];
        float sc = part[1024 + t] + part[1280 + t] + part[1536 + t] + part[1792 + t];
        float sp = part[2048 + t] + part[2304 + t] + part[2560 + t] + part[2816 + t];
#pragma unroll
        for (int off = 32; off > 0; off >>= 1) {
            so += __shfl_xor(so, off);
            sc += __shfl_xor(sc, off);
            sp += __shfl_xor(sp, off);
        }
        if (lane == 0) { fin[wv] = so; fin[4 + wv] = sc; fin[8 + wv] = sp; }
        __syncthreads();
        if (t == 0) {
            dout[16777216]     = (fin[0] + fin[1] + fin[2] + fin[3]) / 16384.f;
            dout[16777216 + 1] = -(fin[4] + fin[5] + fin[6] + fin[7]) / 262144.f;
            dout[16777216 + 2] = (fin[8] + fin[9] + fin[10] + fin[11]) / 262144.f;
        }
        __syncthreads();
    }

    const int b = blockIdx.z, o0 = blockIdx.y * 128, p0 = blockIdx.x * 128;
    const int wr = wv >> 1, wc = wv & 1;

    f32x4 acc[4][4];
#pragma unroll
    for (int i = 0; i < 4; ++i)
#pragma unroll
        for (int j = 0; j < 4; ++j) acc[i][j] = (f32x4){0.f, 0.f, 0.f, 0.f};

    const int srow = p0 + wv * 32 + (lane >> 2);
    const int scol = (lane & 3) * 8;

    for (int kb = 0; kb < 16; ++kb) {
        const int k0 = kb * 32;
        F4 av[4];
#pragma unroll
        for (int j = 0; j < 4; ++j) {
            const int idx = j * 256 + t, row = idx >> 3, q = idx & 7;
            av[j].v = *(const float4*)&w[(size_t)(o0 + row) * 512 + k0 + q * 4];
        }
        __syncthreads();
#pragma unroll
        for (int j = 0; j < 4; ++j) {
            const int idx = j * 256 + t, row = idx >> 3, q = idx & 7;
            H4 hh;
#pragma unroll
            for (int i = 0; i < 4; ++i) hh.h[i] = (_Float16)(av[j].f[i] * 256.f);
            *(uint2*)&Ah[row * 32 + q * 4] = hh.u;
        }
        // B from outpT [b][head=kb>>1][p][c0 = (kb&1)*32 .. +32]
        const _Float16* bsrc = outpT + (((size_t)b * 8 + (kb >> 1)) * 1024 + srow) * 64
                               + (kb & 1) * 32 + scol;
        gld16(bsrc,            &Bh[(wv * 32) * 32]);
        gld16(bsrc + 16 * 64,  &Bh[(wv * 32 + 16) * 32]);
        __syncthreads();
        f16x8 ah[4], bh[4];
#pragma unroll
        for (int i = 0; i < 4; ++i) {
            ah[i] = *(f16x8*)&Ah[(wr * 64 + i * 16 + (lane & 15)) * 32 + (lane >> 4) * 8];
            bh[i] = *(f16x8*)&Bh[(wc * 64 + i * 16 + (lane & 15)) * 32 + (lane >> 4) * 8];
        }
#pragma unroll
        for (int mi = 0; mi < 4; ++mi)
#pragma unroll
            for (int nj = 0; nj < 4; ++nj)
                acc[mi][nj] = __builtin_amdgcn_mfma_f32_16x16x32_f16(ah[mi], bh[nj], acc[mi][nj], 0, 0, 0);
    }
#pragma unroll
    for (int mi = 0; mi < 4; ++mi)
#pragma unroll
        for (int r = 0; r < 4; ++r) {
            const int o = o0 + wr * 64 + mi * 16 + (lane >> 4) * 4 + r;
            const float bs = bias[o];
#pragma unroll
            for (int nj = 0; nj < 4; ++nj) {
                const int p = p0 + wc * 64 + nj * 16 + (lane & 15);
                dout[((size_t)b * 512 + o) * HW + p] = acc[mi][nj][r] * (1.f / 256.f) + bs;
            }
        }
}

extern "C" void kernel_launch(void* const* d_in, const int* in_sizes, int n_in,
                              void* d_out, int out_size, void* d_ws, size_t ws_size,
                              hipStream_t stream)
{
    const float* x   = (const float*)d_in[0];
    const float* f_w = (const float*)d_in[1];
    const float* f_b = (const float*)d_in[2];
    const float* v_w = (const float*)d_in[3];
    const float* v_b = (const float*)d_in[4];
    const float* p_w = (const float*)d_in[5];
    const float* p_b = (const float*)d_in[6];
    const float* s_a = (const float*)d_in[7];
    const float* s_b = (const float*)d_in[8];
    float* out = (float*)d_out;

    char* ws = (char*)d_ws;
    float*     feat    = (float*)ws;                                   // [0, 64M)
    _Float16*  xh      = (_Float16*)(ws + (size_t)64 * 1024 * 1024);   // [64M, 96M)
    _Float16*  xl      = (_Float16*)(ws + (size_t)96 * 1024 * 1024);   // [96M, 128M)
    _Float16*  outpT   = xh;                                           // reuse after k_value
    _Float16*  value_h = xl;                                           // reuse after k_feat
    float*     part    = (float*)(ws + (size_t)128 * 1024 * 1024);     // 12 KB

    k_xsplit <<<dim3(16, 8, 32), 256, 0, stream>>>(x, xh, xl);
    k_feat   <<<dim3(8, 4, 32), 256, 0, stream>>>(f_w, f_b, xh, xl, feat);
    k_value  <<<dim3(8, 4, 32), 256, 0, stream>>>(v_w, v_b, xh, value_h);
    k_cluster<<<dim3(1024), 256, 0, stream>>>(feat, value_h, s_a, s_b, outpT, part);
    k_proj   <<<dim3(8, 4, 32), 256, 0, stream>>>(p_w, p_b, outpT, part, out);
}

// Round 4
// 231.198 us; speedup vs baseline: 3.1022x; 1.0018x over previous
//
#include <hip/hip_runtime.h>

// ---------------------------------------------------------------------------
// Round 3: k_cluster rewrite (streaming centers, fp16 value tile, parallel agg,
// coalesced outpT in [b][8][1024][64] layout) + k_proj B-staging for new layout.
// k_xsplit / k_feat / k_value unchanged from round 2.
// ws: [0,64M) feat fp32 | [64M,96M) xh -> outpT | [96M,128M) xl -> value_h | +12KB part
// ---------------------------------------------------------------------------

#define HW 1024

typedef _Float16 f16x8 __attribute__((ext_vector_type(8)));
typedef float f32x4 __attribute__((ext_vector_type(4)));

union H4 { uint2 u; _Float16 h[4]; };
union H8 { uint4 u; _Float16 h[8]; };
union H2 { unsigned int u; _Float16 h[2]; };
union F4 { float4 v; float f[4]; };

__device__ __forceinline__ void gld16(const _Float16* g, _Float16* l) {
    __builtin_amdgcn_global_load_lds(
        (const __attribute__((address_space(1))) void*)g,
        (__attribute__((address_space(3))) void*)l, 16, 0, 0);
}

// ---------------- k_xsplit: transpose + fp16 split (unchanged) ----------------
__global__ __launch_bounds__(256) void k_xsplit(
    const float* __restrict__ x,
    _Float16* __restrict__ xh, _Float16* __restrict__ xl)
{
    __shared__ float tile[64][65];
    const int t = threadIdx.x;
    const int b = blockIdx.z;
    const int k0 = blockIdx.y * 64;
    const int n0 = blockIdx.x * 64;
    const float* Xb = x + (size_t)b * (512 * HW);

#pragma unroll
    for (int j = 0; j < 16; ++j) {
        const int k = j * 4 + (t >> 6);
        const int n = t & 63;
        tile[k][n] = Xb[(size_t)(k0 + k) * HW + n0 + n];
    }
    __syncthreads();
#pragma unroll
    for (int j = 0; j < 8; ++j) {
        const int n = j * 8 + (t >> 5);
        const int kp = t & 31;
        const float s0 = tile[kp * 2][n] * 256.f;
        const float s1 = tile[kp * 2 + 1][n] * 256.f;
        H2 hh, hl;
        hh.h[0] = (_Float16)s0;
        hh.h[1] = (_Float16)s1;
        hl.h[0] = (_Float16)(s0 - (float)hh.h[0]);
        hl.h[1] = (_Float16)(s1 - (float)hh.h[1]);
        const size_t o = ((size_t)b * 1024 + n0 + n) * 512 + k0 + kp * 2;
        *(unsigned int*)&xh[o] = hh.u;
        *(unsigned int*)&xl[o] = hl.u;
    }
}

// ---------------- k_feat: 3-term split MFMA GEMM (unchanged) ----------------
__global__ __launch_bounds__(256) void k_feat(
    const float* __restrict__ w, const float* __restrict__ bias,
    const _Float16* __restrict__ xh, const _Float16* __restrict__ xl,
    float* __restrict__ feat)
{
    __shared__ _Float16 Ah[128 * 32], Al[128 * 32], Bh[128 * 32], Bl[128 * 32];
    const int t = threadIdx.x, lane = t & 63, wv = t >> 6;
    const int b = blockIdx.z, o0 = blockIdx.y * 128, p0 = blockIdx.x * 128;
    const int wr = wv >> 1, wc = wv & 1;

    f32x4 acc[4][4];
#pragma unroll
    for (int i = 0; i < 4; ++i)
#pragma unroll
        for (int j = 0; j < 4; ++j) acc[i][j] = (f32x4){0.f, 0.f, 0.f, 0.f};

    const size_t brow = (size_t)b * 1024 + p0 + wv * 32 + (lane >> 2);
    const _Float16* bsh = xh + brow * 512 + (lane & 3) * 8;
    const _Float16* bsl = xl + brow * 512 + (lane & 3) * 8;

    for (int kb = 0; kb < 16; ++kb) {
        const int k0 = kb * 32;
        F4 av[4];
#pragma unroll
        for (int j = 0; j < 4; ++j) {
            const int idx = j * 256 + t, row = idx >> 3, q = idx & 7;
            av[j].v = *(const float4*)&w[(size_t)(o0 + row) * 512 + k0 + q * 4];
        }
        __syncthreads();
#pragma unroll
        for (int j = 0; j < 4; ++j) {
            const int idx = j * 256 + t, row = idx >> 3, q = idx & 7;
            H4 hh, hl;
#pragma unroll
            for (int i = 0; i < 4; ++i) {
                const float s = av[j].f[i] * 256.f;
                const _Float16 h = (_Float16)s;
                hh.h[i] = h;
                hl.h[i] = (_Float16)(s - (float)h);
            }
            *(uint2*)&Ah[row * 32 + q * 4] = hh.u;
            *(uint2*)&Al[row * 32 + q * 4] = hl.u;
        }
#pragma unroll
        for (int j = 0; j < 2; ++j) {
            gld16(bsh + (size_t)(j * 16) * 512 + k0, &Bh[(wv * 32 + j * 16) * 32]);
            gld16(bsl + (size_t)(j * 16) * 512 + k0, &Bl[(wv * 32 + j * 16) * 32]);
        }
        __syncthreads();
        f16x8 ah[4], al[4], bh[4], bl[4];
#pragma unroll
        for (int i = 0; i < 4; ++i) {
            const int ao = (wr * 64 + i * 16 + (lane & 15)) * 32 + (lane >> 4) * 8;
            const int bo = (wc * 64 + i * 16 + (lane & 15)) * 32 + (lane >> 4) * 8;
            ah[i] = *(f16x8*)&Ah[ao];
            al[i] = *(f16x8*)&Al[ao];
            bh[i] = *(f16x8*)&Bh[bo];
            bl[i] = *(f16x8*)&Bl[bo];
        }
#pragma unroll
        for (int mi = 0; mi < 4; ++mi)
#pragma unroll
            for (int nj = 0; nj < 4; ++nj) {
                acc[mi][nj] = __builtin_amdgcn_mfma_f32_16x16x32_f16(ah[mi], bh[nj], acc[mi][nj], 0, 0, 0);
                acc[mi][nj] = __builtin_amdgcn_mfma_f32_16x16x32_f16(ah[mi], bl[nj], acc[mi][nj], 0, 0, 0);
                acc[mi][nj] = __builtin_amdgcn_mfma_f32_16x16x32_f16(al[mi], bh[nj], acc[mi][nj], 0, 0, 0);
            }
    }
#pragma unroll
    for (int mi = 0; mi < 4; ++mi)
#pragma unroll
        for (int r = 0; r < 4; ++r) {
            const int o = o0 + wr * 64 + mi * 16 + (lane >> 4) * 4 + r;
            const float bs = bias[o];
#pragma unroll
            for (int nj = 0; nj < 4; ++nj) {
                const int p = p0 + wc * 64 + nj * 16 + (lane & 15);
                feat[((size_t)b * 512 + o) * HW + p] = acc[mi][nj][r] * (1.f / 65536.f) + bs;
            }
        }
}

// ---------------- k_value: 1-term MFMA GEMM, fp16 out (unchanged) ----------------
__global__ __launch_bounds__(256) void k_value(
    const float* __restrict__ w, const float* __restrict__ bias,
    const _Float16* __restrict__ xh, _Float16* __restrict__ value_h)
{
    __shared__ _Float16 Ah[128 * 32], Bh[128 * 32];
    const int t = threadIdx.x, lane = t & 63, wv = t >> 6;
    const int b = blockIdx.z, o0 = blockIdx.y * 128, p0 = blockIdx.x * 128;
    const int wr = wv >> 1, wc = wv & 1;

    f32x4 acc[4][4];
#pragma unroll
    for (int i = 0; i < 4; ++i)
#pragma unroll
        for (int j = 0; j < 4; ++j) acc[i][j] = (f32x4){0.f, 0.f, 0.f, 0.f};

    const _Float16* bsh = xh + ((size_t)b * 1024 + p0 + wv * 32 + (lane >> 2)) * 512 + (lane & 3) * 8;

    for (int kb = 0; kb < 16; ++kb) {
        const int k0 = kb * 32;
        F4 av[4];
#pragma unroll
        for (int j = 0; j < 4; ++j) {
            const int idx = j * 256 + t, row = idx >> 3, q = idx & 7;
            av[j].v = *(const float4*)&w[(size_t)(o0 + row) * 512 + k0 + q * 4];
        }
        __syncthreads();
#pragma unroll
        for (int j = 0; j < 4; ++j) {
            const int idx = j * 256 + t, row = idx >> 3, q = idx & 7;
            H4 hh;
#pragma unroll
            for (int i = 0; i < 4; ++i) hh.h[i] = (_Float16)(av[j].f[i] * 256.f);
            *(uint2*)&Ah[row * 32 + q * 4] = hh.u;
        }
#pragma unroll
        for (int j = 0; j < 2; ++j)
            gld16(bsh + (size_t)(j * 16) * 512 + k0, &Bh[(wv * 32 + j * 16) * 32]);
        __syncthreads();
        f16x8 ah[4], bh[4];
#pragma unroll
        for (int i = 0; i < 4; ++i) {
            ah[i] = *(f16x8*)&Ah[(wr * 64 + i * 16 + (lane & 15)) * 32 + (lane >> 4) * 8];
            bh[i] = *(f16x8*)&Bh[(wc * 64 + i * 16 + (lane & 15)) * 32 + (lane >> 4) * 8];
        }
#pragma unroll
        for (int mi = 0; mi < 4; ++mi)
#pragma unroll
            for (int nj = 0; nj < 4; ++nj)
                acc[mi][nj] = __builtin_amdgcn_mfma_f32_16x16x32_f16(ah[mi], bh[nj], acc[mi][nj], 0, 0, 0);
    }
#pragma unroll
    for (int mi = 0; mi < 4; ++mi)
#pragma unroll
        for (int r = 0; r < 4; ++r) {
            const int o = o0 + wr * 64 + mi * 16 + (lane >> 4) * 4 + r;
            const float bs = bias[o];
#pragma unroll
            for (int nj = 0; nj < 4; ++nj) {
                const int p = p0 + wc * 64 + nj * 16 + (lane & 15);
                value_h[((size_t)b * 512 + o) * HW + p] =
                    (_Float16)(acc[mi][nj][r] * (1.f / 65536.f) + bs);
            }
        }
}

// ---------------- k_cluster: streaming rewrite ----------------
// one block per folded batch; 256 threads.
// LDS ~41 KB -> 3 blocks/CU (was 68 KB -> 2).
__global__ __launch_bounds__(256) void k_cluster(
    const float* __restrict__ feat,
    const _Float16* __restrict__ value_h,
    const float* __restrict__ alpha_p, const float* __restrict__ beta_p,
    _Float16* __restrict__ outpT,          // [b][8][1024][64] fp16
    float* __restrict__ part)
{
    __shared__ _Float16 vbuf[256 * 64];    // 32 KB swizzled value tile
    __shared__ float cnl[4][64];           // centers -> normalized centers
    __shared__ float vcl[4][64];           // value centers
    __shared__ float obuf[4][68];          // cluster outputs (padded)
    __shared__ int   sidx[256];
    __shared__ float sbest[256];
    __shared__ float scrt[4][4][64];       // per-wave agg partials
    __shared__ int   cntw[4][4];
    __shared__ float cinv[4];
    __shared__ float red[8];
    __shared__ float gsc[16];

    const int t = threadIdx.x, lane = t & 63, wv = t >> 6;
    const int bp = blockIdx.x;
    const int f2 = bp & 1, f1 = (bp >> 1) & 1, head = (bp >> 2) & 7, b = bp >> 5;
    const size_t base = ((size_t)b * 512 + head * 64) * HW + f1 * 512 + f2 * 16;

    // ---- phase A: feat centers by streaming + shfl groups ----
    // lane l loads float4 = points n=4l..4l+3 (all share center m):
    //   m = ((l>>5)<<1) | ((l>>1)&1); reduce over lane bits {0,2,3,4}
    const int sp4 = (lane >> 2) * 32 + (lane & 3) * 4;
    const int mA = ((lane >> 5) << 1) | ((lane >> 1) & 1);
#pragma unroll
    for (int i = 0; i < 16; ++i) {
        const int c = wv * 16 + i;
        F4 v;
        v.v = *(const float4*)&feat[base + (size_t)c * HW + sp4];
        float s = (v.f[0] + v.f[1]) + (v.f[2] + v.f[3]);
        s += __shfl_xor(s, 1);
        s += __shfl_xor(s, 4);
        s += __shfl_xor(s, 8);
        s += __shfl_xor(s, 16);
        if ((lane & 29) == 0) cnl[mA][c] = s * (1.f / 64.f);   // lanes 0,2,32,34
    }
    __syncthreads();

    // ---- center norms, normalize in place ----
    const int m = t >> 6, cc = lane;
    {
        const float fc = cnl[m][cc];
        float ss = fc * fc;
#pragma unroll
        for (int off = 32; off > 0; off >>= 1) ss += __shfl_xor(ss, off);
        if (lane == 0) cinv[m] = 1.f / fmaxf(sqrtf(ss), 1e-12f);
        __syncthreads();
        cnl[m][cc] = fc * cinv[m];
    }
    __syncthreads();

    // ---- G / L_Orth partial (normalized centers) ----
    if (t < 16) {
        const int gm = t >> 2, gk = t & 3;
        float g = 0.f;
        for (int c = 0; c < 64; ++c) g += cnl[gm][c] * cnl[gk][c];
        const float d = g - (gm == gk ? 1.f : 0.f);
        gsc[t] = d * d;
    }

    // ---- phase B: per-point dots (stream feat again, L2-hot) ----
    const float alpha = alpha_p[0], beta = beta_p[0];
    const int n = t;
    const int spn = (n >> 4) * 32 + (n & 15);
    float ssf = 0.f, d0 = 0.f, d1 = 0.f, d2 = 0.f, d3 = 0.f;
#pragma unroll
    for (int c4 = 0; c4 < 16; ++c4) {
        float fv[4];
#pragma unroll
        for (int j = 0; j < 4; ++j)
            fv[j] = feat[base + (size_t)(c4 * 4 + j) * HW + spn];
        const float4 c0 = *(const float4*)&cnl[0][c4 * 4];
        const float4 c1 = *(const float4*)&cnl[1][c4 * 4];
        const float4 c2 = *(const float4*)&cnl[2][c4 * 4];
        const float4 c3 = *(const float4*)&cnl[3][c4 * 4];
        ssf += fv[0]*fv[0] + fv[1]*fv[1] + fv[2]*fv[2] + fv[3]*fv[3];
        d0 += fv[0]*c0.x + fv[1]*c0.y + fv[2]*c0.z + fv[3]*c0.w;
        d1 += fv[0]*c1.x + fv[1]*c1.y + fv[2]*c1.z + fv[3]*c1.w;
        d2 += fv[0]*c2.x + fv[1]*c2.y + fv[2]*c2.z + fv[3]*c2.w;
        d3 += fv[0]*c3.x + fv[1]*c3.y + fv[2]*c3.z + fv[3]*c3.w;
    }
    const float invf = 1.f / fmaxf(sqrtf(ssf), 1e-12f);
    float simv[4];
    simv[0] = d0 * invf;
    simv[1] = d1 * invf;
    simv[2] = d2 * invf;
    simv[3] = d3 * invf;
#pragma unroll
    for (int mm = 0; mm < 4; ++mm)
        simv[mm] = 1.f / (1.f + expf(-(beta + alpha * simv[mm])));
    float best = simv[0], second = -1.f;
    int idx = 0;
#pragma unroll
    for (int mm = 1; mm < 4; ++mm) {
        if (simv[mm] > best) { second = best; best = simv[mm]; idx = mm; }
        else second = fmaxf(second, simv[mm]);
    }
    sidx[n] = idx;
    sbest[n] = best;

    // ---- phase D: stage value tile (fp16, swizzled) ----
    // half-word index: v_idx(n,c) = n*64 + (c ^ (((n>>2)&31)<<1))
#pragma unroll
    for (int i = 0; i < 16; ++i) {
        const int q = i * 256 + t;
        const int c = q >> 6;
        const int n0 = (q & 63) * 4;
        H4 v;
        v.u = *(const uint2*)&value_h[base + (size_t)c * HW + (n0 >> 4) * 32 + (n0 & 15)];
        const int swz = ((n0 >> 2) & 31) << 1;
#pragma unroll
        for (int j = 0; j < 4; ++j)
            vbuf[(n0 + j) * 64 + (c ^ swz)] = v.h[j];
    }

    // ---- loss partial reduce ----
    float bsum = best, s2sum = second;
#pragma unroll
    for (int off = 32; off > 0; off >>= 1) {
        bsum += __shfl_xor(bsum, off);
        s2sum += __shfl_xor(s2sum, off);
    }
    if (lane == 0) { red[wv] = bsum; red[4 + wv] = s2sum; }
    __syncthreads();   // covers gsc, red, sidx, sbest, vbuf
    if (t == 0) {
        part[bp]        = gsc[0] + gsc[1] + gsc[2] + gsc[3] + gsc[4] + gsc[5] + gsc[6] + gsc[7]
                        + gsc[8] + gsc[9] + gsc[10] + gsc[11] + gsc[12] + gsc[13] + gsc[14] + gsc[15];
        part[1024 + bp] = red[0] + red[1] + red[2] + red[3];
        part[2048 + bp] = red[4] + red[5] + red[6] + red[7];
    }

    // ---- value centers from vbuf: thread (m, cc) ----
    {
        const int pi = m >> 1, pj = m & 1;
        float vcs = 0.f;
#pragma unroll
        for (int wp = 0; wp < 8; ++wp)
#pragma unroll
            for (int hp = 0; hp < 8; ++hp) {
                const int nn = (pi * 8 + wp) * 16 + pj * 8 + hp;
                vcs += (float)vbuf[nn * 64 + (cc ^ (((nn >> 2) & 31) << 1))];
            }
        vcl[m][cc] = vcs * (1.f / 64.f);
    }

    // ---- phase E: parallel agg scan (wave wv covers 64 points) ----
    {
        float ag0 = 0.f, ag1 = 0.f, ag2 = 0.f, ag3 = 0.f;
        int c0i = 0, c1i = 0, c2i = 0, c3i = 0;
        for (int j = 0; j < 64; ++j) {
            const int nn = wv * 64 + j;
            const int id = sidx[nn];
            const float v = (float)vbuf[nn * 64 + (cc ^ (((nn >> 2) & 31) << 1))];
            ag0 += (id == 0) ? v : 0.f;  c0i += (id == 0);
            ag1 += (id == 1) ? v : 0.f;  c1i += (id == 1);
            ag2 += (id == 2) ? v : 0.f;  c2i += (id == 2);
            ag3 += (id == 3) ? v : 0.f;  c3i += (id == 3);
        }
        scrt[wv][0][cc] = ag0;
        scrt[wv][1][cc] = ag1;
        scrt[wv][2][cc] = ag2;
        scrt[wv][3][cc] = ag3;
        if (lane == 0) {
            cntw[wv][0] = c0i; cntw[wv][1] = c1i;
            cntw[wv][2] = c2i; cntw[wv][3] = c3i;
        }
    }
    __syncthreads();

    // ---- cluster outputs ----
    {
        const float a = scrt[0][m][cc] + scrt[1][m][cc] + scrt[2][m][cc] + scrt[3][m][cc];
        const int c = cntw[0][m] + cntw[1][m] + cntw[2][m] + cntw[3][m];
        obuf[m][cc] = (a + vcl[m][cc]) / (float)(c + 1);
    }
    __syncthreads();

    // ---- phase F: coalesced outpT write (4 lanes per point, 2KB/wave-store) ----
    const int cch = (t & 3) * 16;
#pragma unroll
    for (int r = 0; r < 4; ++r) {
        const int nn = r * 64 + (t >> 2);
        const int id = sidx[nn];
        const float bs = sbest[nn];
        const int p = (f1 * 16 + (nn >> 4)) * 32 + f2 * 16 + (nn & 15);
        _Float16* dst = outpT + (((size_t)b * 8 + head) * 1024 + p) * 64 + cch;
        const float4 oa = *(const float4*)&obuf[id][cch];
        const float4 ob = *(const float4*)&obuf[id][cch + 4];
        const float4 oc = *(const float4*)&obuf[id][cch + 8];
        const float4 od = *(const float4*)&obuf[id][cch + 12];
        H8 w0, w1;
        w0.h[0] = (_Float16)(bs * oa.x); w0.h[1] = (_Float16)(bs * oa.y);
        w0.h[2] = (_Float16)(bs * oa.z); w0.h[3] = (_Float16)(bs * oa.w);
        w0.h[4] = (_Float16)(bs * ob.x); w0.h[5] = (_Float16)(bs * ob.y);
        w0.h[6] = (_Float16)(bs * ob.z); w0.h[7] = (_Float16)(bs * ob.w);
        w1.h[0] = (_Float16)(bs * oc.x); w1.h[1] = (_Float16)(bs * oc.y);
        w1.h[2] = (_Float16)(bs * oc.z); w1.h[3] = (_Float16)(bs * oc.w);
        w1.h[4] = (_Float16)(bs * od.x); w1.h[5] = (_Float16)(bs * od.y);
        w1.h[6] = (_Float16)(bs * od.z); w1.h[7] = (_Float16)(bs * od.w);
        *(uint4*)dst = w0.u;
        *(uint4*)(dst + 8) = w1.u;
    }
}

// ---------------- k_proj: MFMA GEMM over outpT[b][8][1024][64] + loss finalize ----------------
__global__ __launch_bounds__(256) void k_proj(
    const float* __restrict__ w, const float* __restrict__ bias,
    const _Float16* __restrict__ outpT,
    const float* __restrict__ part,
    float* __restrict__ dout)
{
    __shared__ _Float16 Ah[128 * 32], Bh[128 * 32];
    __shared__ float fin[12];
    const int t = threadIdx.x, lane = t & 63, wv = t >> 6;

    if (blockIdx.x == 0 && blockIdx.y == 0 && blockIdx.z == 0) {
        float so = part[t] + part[t + 256] + part[t + 512] + part[t + 768];
        float sc = part[1024 + t] + part[1280 + t] + part[1536 + t] + part[1792 + t];
        float sp = part[2048 + t] + part[2304 + t] + part[2560 + t] + part[2816 + t];
#pragma unroll
        for (int off = 32; off > 0; off >>= 1) {
            so += __shfl_xor(so, off);
            sc += __shfl_xor(sc, off);
            sp += __shfl_xor(sp, off);
        }
        if (lane == 0) { fin[wv] = so; fin[4 + wv] = sc; fin[8 + wv] = sp; }
        __syncthreads();
        if (t == 0) {
            dout[16777216]     = (fin[0] + fin[1] + fin[2] + fin[3]) / 16384.f;
            dout[16777216 + 1] = -(fin[4] + fin[5] + fin[6] + fin[7]) / 262144.f;
            dout[16777216 + 2] = (fin[8] + fin[9] + fin[10] + fin[11]) / 262144.f;
        }
        __syncthreads();
    }

    const int b = blockIdx.z, o0 = blockIdx.y * 128, p0 = blockIdx.x * 128;
    const int wr = wv >> 1, wc = wv & 1;

    f32x4 acc[4][4];
#pragma unroll
    for (int i = 0; i < 4; ++i)
#pragma unroll
        for (int j = 0; j < 4; ++j) acc[i][j] = (f32x4){0.f, 0.f, 0.f, 0.f};

    const int srow = p0 + wv * 32 + (lane >> 2);
    const int scol = (lane & 3) * 8;

    for (int kb = 0; kb < 16; ++kb) {
        const int k0 = kb * 32;
        F4 av[4];
#pragma unroll
        for (int j = 0; j < 4; ++j) {
            const int idx = j * 256 + t, row = idx >> 3, q = idx & 7;
            av[j].v = *(const float4*)&w[(size_t)(o0 + row) * 512 + k0 + q * 4];
        }
        __syncthreads();
#pragma unroll
        for (int j = 0; j < 4; ++j) {
            const int idx = j * 256 + t, row = idx >> 3, q = idx & 7;
            H4 hh;
#pragma unroll
            for (int i = 0; i < 4; ++i) hh.h[i] = (_Float16)(av[j].f[i] * 256.f);
            *(uint2*)&Ah[row * 32 + q * 4] = hh.u;
        }
        // B from outpT [b][head=kb>>1][p][c0 = (kb&1)*32 .. +32]
        const _Float16* bsrc = outpT + (((size_t)b * 8 + (kb >> 1)) * 1024 + srow) * 64
                               + (kb & 1) * 32 + scol;
        gld16(bsrc,            &Bh[(wv * 32) * 32]);
        gld16(bsrc + 16 * 64,  &Bh[(wv * 32 + 16) * 32]);
        __syncthreads();
        f16x8 ah[4], bh[4];
#pragma unroll
        for (int i = 0; i < 4; ++i) {
            ah[i] = *(f16x8*)&Ah[(wr * 64 + i * 16 + (lane & 15)) * 32 + (lane >> 4) * 8];
            bh[i] = *(f16x8*)&Bh[(wc * 64 + i * 16 + (lane & 15)) * 32 + (lane >> 4) * 8];
        }
#pragma unroll
        for (int mi = 0; mi < 4; ++mi)
#pragma unroll
            for (int nj = 0; nj < 4; ++nj)
                acc[mi][nj] = __builtin_amdgcn_mfma_f32_16x16x32_f16(ah[mi], bh[nj], acc[mi][nj], 0, 0, 0);
    }
#pragma unroll
    for (int mi = 0; mi < 4; ++mi)
#pragma unroll
        for (int r = 0; r < 4; ++r) {
            const int o = o0 + wr * 64 + mi * 16 + (lane >> 4) * 4 + r;
            const float bs = bias[o];
#pragma unroll
            for (int nj = 0; nj < 4; ++nj) {
                const int p = p0 + wc * 64 + nj * 16 + (lane & 15);
                dout[((size_t)b * 512 + o) * HW + p] = acc[mi][nj][r] * (1.f / 256.f) + bs;
            }
        }
}

extern "C" void kernel_launch(void* const* d_in, const int* in_sizes, int n_in,
                              void* d_out, int out_size, void* d_ws, size_t ws_size,
                              hipStream_t stream)
{
    const float* x   = (const float*)d_in[0];
    const float* f_w = (const float*)d_in[1];
    const float* f_b = (const float*)d_in[2];
    const float* v_w = (const float*)d_in[3];
    const float* v_b = (const float*)d_in[4];
    const float* p_w = (const float*)d_in[5];
    const float* p_b = (const float*)d_in[6];
    const float* s_a = (const float*)d_in[7];
    const float* s_b = (const float*)d_in[8];
    float* out = (float*)d_out;

    char* ws = (char*)d_ws;
    float*     feat    = (float*)ws;                                   // [0, 64M)
    _Float16*  xh      = (_Float16*)(ws + (size_t)64 * 1024 * 1024);   // [64M, 96M)
    _Float16*  xl      = (_Float16*)(ws + (size_t)96 * 1024 * 1024);   // [96M, 128M)
    _Float16*  outpT   = xh;                                           // reuse after k_value
    _Float16*  value_h = xl;                                           // reuse after k_feat
    float*     part    = (float*)(ws + (size_t)128 * 1024 * 1024);     // 12 KB

    k_xsplit <<<dim3(16, 8, 32), 256, 0, stream>>>(x, xh, xl);
    k_feat   <<<dim3(8, 4, 32), 256, 0, stream>>>(f_w, f_b, xh, xl, feat);
    k_value  <<<dim3(8, 4, 32), 256, 0, stream>>>(v_w, v_b, xh, value_h);
    k_cluster<<<dim3(1024), 256, 0, stream>>>(feat, value_h, s_a, s_b, outpT, part);
    k_proj   <<<dim3(8, 4, 32), 256, 0, stream>>>(p_w, p_b, outpT, part, out);
}

// Round 5
// 201.996 us; speedup vs baseline: 3.5507x; 1.1446x over previous
//
#include <hip/hip_runtime.h>

// ---------------------------------------------------------------------------
// Round 5:
//  k_wsplit : pre-split f_w (hi+lo) and v_w (hi) to fp16, scaled by 2^8
//  k_xsplit : unchanged (x -> xh/xl fp16 [b][n][k])
//  k_feat   : 3-term MFMA GEMM, A staged via gld16 from pre-split weights;
//             writes feat_T [b][1024 p][512 c] fp32 + pooled center partials
//  k_value  : 1-term MFMA GEMM, writes value_T [b][1024 p][512 c] fp16 +
//             pooled value-center partials
//  k_cluster: centers from partials (no feat pre-pass); single feat stream;
//             agg scan; coalesced outpT [b][8][1024][64] fp16
//  k_proj   : unchanged round-3 structure (runtime w conversion) + losses
// ws: [0,64M) feat_T | [64M,96M) xh->outpT | [96M,128M) xl->value_T | +12KB part
// d_out scratch (consumed before k_proj writes): fwh, fwl, vwh, centers_f/v
// ---------------------------------------------------------------------------

#define HW 1024

typedef _Float16 f16x8 __attribute__((ext_vector_type(8)));
typedef float f32x4 __attribute__((ext_vector_type(4)));

union H4 { uint2 u; _Float16 h[4]; };
union H8 { uint4 u; _Float16 h[8]; };
union H2 { unsigned int u; _Float16 h[2]; };
union F4 { float4 v; float f[4]; };

__device__ __forceinline__ void gld16(const _Float16* g, _Float16* l) {
    __builtin_amdgcn_global_load_lds(
        (const __attribute__((address_space(1))) void*)g,
        (__attribute__((address_space(3))) void*)l, 16, 0, 0);
}

// ---------------- k_wsplit: pre-split weights ----------------
// grid 256 x 256 threads; idx covers 512*512/4 float4s
__global__ __launch_bounds__(256) void k_wsplit(
    const float* __restrict__ fw, const float* __restrict__ vw,
    _Float16* __restrict__ fwh, _Float16* __restrict__ fwl,
    _Float16* __restrict__ vwh)
{
    const int i = (blockIdx.x * 256 + threadIdx.x) * 4;
    F4 a;
    a.v = *(const float4*)&fw[i];
    H4 h, l;
#pragma unroll
    for (int j = 0; j < 4; ++j) {
        const float s = a.f[j] * 256.f;
        h.h[j] = (_Float16)s;
        l.h[j] = (_Float16)(s - (float)h.h[j]);
    }
    *(uint2*)&fwh[i] = h.u;
    *(uint2*)&fwl[i] = l.u;
    a.v = *(const float4*)&vw[i];
#pragma unroll
    for (int j = 0; j < 4; ++j) h.h[j] = (_Float16)(a.f[j] * 256.f);
    *(uint2*)&vwh[i] = h.u;
}

// ---------------- k_xsplit: transpose + fp16 split (unchanged) ----------------
__global__ __launch_bounds__(256) void k_xsplit(
    const float* __restrict__ x,
    _Float16* __restrict__ xh, _Float16* __restrict__ xl)
{
    __shared__ float tile[64][65];
    const int t = threadIdx.x;
    const int b = blockIdx.z;
    const int k0 = blockIdx.y * 64;
    const int n0 = blockIdx.x * 64;
    const float* Xb = x + (size_t)b * (512 * HW);

#pragma unroll
    for (int j = 0; j < 16; ++j) {
        const int k = j * 4 + (t >> 6);
        const int n = t & 63;
        tile[k][n] = Xb[(size_t)(k0 + k) * HW + n0 + n];
    }
    __syncthreads();
#pragma unroll
    for (int j = 0; j < 8; ++j) {
        const int n = j * 8 + (t >> 5);
        const int kp = t & 31;
        const float s0 = tile[kp * 2][n] * 256.f;
        const float s1 = tile[kp * 2 + 1][n] * 256.f;
        H2 hh, hl;
        hh.h[0] = (_Float16)s0;
        hh.h[1] = (_Float16)s1;
        hl.h[0] = (_Float16)(s0 - (float)hh.h[0]);
        hl.h[1] = (_Float16)(s1 - (float)hh.h[1]);
        const size_t o = ((size_t)b * 1024 + n0 + n) * 512 + k0 + kp * 2;
        *(unsigned int*)&xh[o] = hh.u;
        *(unsigned int*)&xl[o] = hl.u;
    }
}

// ---------------- k_feat: 3-term split MFMA, gld16 A-staging, feat_T out ----------------
// grid (8 p-tiles, 4 o-tiles, 32 b), block 256 (4 waves, 2x2)
__global__ __launch_bounds__(256) void k_feat(
    const _Float16* __restrict__ fwh, const _Float16* __restrict__ fwl,
    const float* __restrict__ bias,
    const _Float16* __restrict__ xh, const _Float16* __restrict__ xl,
    float* __restrict__ feat_T, float* __restrict__ centers_f)
{
    __shared__ _Float16 Ah[128 * 32], Al[128 * 32], Bh[128 * 32], Bl[128 * 32];
    __shared__ float pool_lds[2][128][4];
    const int t = threadIdx.x, lane = t & 63, wv = t >> 6;
    const int b = blockIdx.z, o0 = blockIdx.y * 128, p0 = blockIdx.x * 128;
    const int wr = wv >> 1, wc = wv & 1;

    f32x4 acc[4][4];
#pragma unroll
    for (int i = 0; i < 4; ++i)
#pragma unroll
        for (int j = 0; j < 4; ++j) acc[i][j] = (f32x4){0.f, 0.f, 0.f, 0.f};

    const _Float16* ash = fwh + (size_t)(o0 + wv * 32 + (lane >> 2)) * 512 + (lane & 3) * 8;
    const _Float16* asl = fwl + (size_t)(o0 + wv * 32 + (lane >> 2)) * 512 + (lane & 3) * 8;
    const size_t brow = (size_t)b * 1024 + p0 + wv * 32 + (lane >> 2);
    const _Float16* bsh = xh + brow * 512 + (lane & 3) * 8;
    const _Float16* bsl = xl + brow * 512 + (lane & 3) * 8;

    for (int kb = 0; kb < 16; ++kb) {
        const int k0 = kb * 32;
        __syncthreads();   // previous iteration's fragment reads complete
#pragma unroll
        for (int j = 0; j < 2; ++j) {
            gld16(ash + (size_t)(j * 16) * 512 + k0, &Ah[(wv * 32 + j * 16) * 32]);
            gld16(asl + (size_t)(j * 16) * 512 + k0, &Al[(wv * 32 + j * 16) * 32]);
            gld16(bsh + (size_t)(j * 16) * 512 + k0, &Bh[(wv * 32 + j * 16) * 32]);
            gld16(bsl + (size_t)(j * 16) * 512 + k0, &Bl[(wv * 32 + j * 16) * 32]);
        }
        __syncthreads();   // compiler drains vmcnt before barrier
        f16x8 ah[4], al[4], bh[4], bl[4];
#pragma unroll
        for (int i = 0; i < 4; ++i) {
            const int ao = (wr * 64 + i * 16 + (lane & 15)) * 32 + (lane >> 4) * 8;
            const int bo = (wc * 64 + i * 16 + (lane & 15)) * 32 + (lane >> 4) * 8;
            ah[i] = *(f16x8*)&Ah[ao];
            al[i] = *(f16x8*)&Al[ao];
            bh[i] = *(f16x8*)&Bh[bo];
            bl[i] = *(f16x8*)&Bl[bo];
        }
#pragma unroll
        for (int mi = 0; mi < 4; ++mi)
#pragma unroll
            for (int nj = 0; nj < 4; ++nj) {
                acc[mi][nj] = __builtin_amdgcn_mfma_f32_16x16x32_f16(ah[mi], bh[nj], acc[mi][nj], 0, 0, 0);
                acc[mi][nj] = __builtin_amdgcn_mfma_f32_16x16x32_f16(ah[mi], bl[nj], acc[mi][nj], 0, 0, 0);
                acc[mi][nj] = __builtin_amdgcn_mfma_f32_16x16x32_f16(al[mi], bh[nj], acc[mi][nj], 0, 0, 0);
            }
    }

    // ---- epilogue: feat_T stores + pooled center partials ----
    const int pj = (lane >> 3) & 1;
    float ps[16][2];
#pragma unroll
    for (int mi = 0; mi < 4; ++mi) {
        const int obase = o0 + wr * 64 + mi * 16 + (lane >> 4) * 4;
        F4 bs4;
        bs4.v = *(const float4*)&bias[obase];
#pragma unroll
        for (int r = 0; r < 4; ++r) { ps[mi * 4 + r][0] = 0.f; ps[mi * 4 + r][1] = 0.f; }
#pragma unroll
        for (int nj = 0; nj < 4; ++nj) {
            const int p = p0 + wc * 64 + nj * 16 + (lane & 15);
            F4 vv;
#pragma unroll
            for (int r = 0; r < 4; ++r) {
                vv.f[r] = acc[mi][nj][r] * (1.f / 65536.f) + bs4.f[r];
                ps[mi * 4 + r][nj & 1] += vv.f[r];
            }
            *(float4*)&feat_T[((size_t)b * 1024 + p) * 512 + obase] = vv.v;
        }
    }
#pragma unroll
    for (int q = 0; q < 16; ++q)
#pragma unroll
        for (int f2s = 0; f2s < 2; ++f2s) {
            ps[q][f2s] += __shfl_xor(ps[q][f2s], 1);
            ps[q][f2s] += __shfl_xor(ps[q][f2s], 2);
            ps[q][f2s] += __shfl_xor(ps[q][f2s], 4);
        }
    if ((lane & 7) == 0) {
#pragma unroll
        for (int mi = 0; mi < 4; ++mi)
#pragma unroll
            for (int r = 0; r < 4; ++r) {
                const int ol = wr * 64 + mi * 16 + (lane >> 4) * 4 + r;
                pool_lds[wc][ol][0 * 2 + pj] = ps[mi * 4 + r][0];
                pool_lds[wc][ol][1 * 2 + pj] = ps[mi * 4 + r][1];
            }
    }
    __syncthreads();
#pragma unroll
    for (int u = 0; u < 2; ++u) {
        const int idx = u * 256 + t;
        const int g = idx >> 7, o = idx & 127;
        centers_f[(((size_t)b * 8 + blockIdx.x) * 4 + g) * 512 + o0 + o] =
            pool_lds[0][o][g] + pool_lds[1][o][g];
    }
}

// ---------------- k_value: 1-term MFMA, value_T fp16 out + center partials ----------------
__global__ __launch_bounds__(256) void k_value(
    const _Float16* __restrict__ vwh, const float* __restrict__ bias,
    const _Float16* __restrict__ xh,
    _Float16* __restrict__ value_T, float* __restrict__ centers_v)
{
    __shared__ _Float16 Ah[128 * 32], Bh[128 * 32];
    __shared__ float pool_lds[2][128][4];
    const int t = threadIdx.x, lane = t & 63, wv = t >> 6;
    const int b = blockIdx.z, o0 = blockIdx.y * 128, p0 = blockIdx.x * 128;
    const int wr = wv >> 1, wc = wv & 1;

    f32x4 acc[4][4];
#pragma unroll
    for (int i = 0; i < 4; ++i)
#pragma unroll
        for (int j = 0; j < 4; ++j) acc[i][j] = (f32x4){0.f, 0.f, 0.f, 0.f};

    const _Float16* ash = vwh + (size_t)(o0 + wv * 32 + (lane >> 2)) * 512 + (lane & 3) * 8;
    const _Float16* bsh = xh + ((size_t)b * 1024 + p0 + wv * 32 + (lane >> 2)) * 512 + (lane & 3) * 8;

    for (int kb = 0; kb < 16; ++kb) {
        const int k0 = kb * 32;
        __syncthreads();
#pragma unroll
        for (int j = 0; j < 2; ++j) {
            gld16(ash + (size_t)(j * 16) * 512 + k0, &Ah[(wv * 32 + j * 16) * 32]);
            gld16(bsh + (size_t)(j * 16) * 512 + k0, &Bh[(wv * 32 + j * 16) * 32]);
        }
        __syncthreads();
        f16x8 ah[4], bh[4];
#pragma unroll
        for (int i = 0; i < 4; ++i) {
            ah[i] = *(f16x8*)&Ah[(wr * 64 + i * 16 + (lane & 15)) * 32 + (lane >> 4) * 8];
            bh[i] = *(f16x8*)&Bh[(wc * 64 + i * 16 + (lane & 15)) * 32 + (lane >> 4) * 8];
        }
#pragma unroll
        for (int mi = 0; mi < 4; ++mi)
#pragma unroll
            for (int nj = 0; nj < 4; ++nj)
                acc[mi][nj] = __builtin_amdgcn_mfma_f32_16x16x32_f16(ah[mi], bh[nj], acc[mi][nj], 0, 0, 0);
    }

    const int pj = (lane >> 3) & 1;
    float ps[16][2];
#pragma unroll
    for (int mi = 0; mi < 4; ++mi) {
        const int obase = o0 + wr * 64 + mi * 16 + (lane >> 4) * 4;
        F4 bs4;
        bs4.v = *(const float4*)&bias[obase];
#pragma unroll
        for (int r = 0; r < 4; ++r) { ps[mi * 4 + r][0] = 0.f; ps[mi * 4 + r][1] = 0.f; }
#pragma unroll
        for (int nj = 0; nj < 4; ++nj) {
            const int p = p0 + wc * 64 + nj * 16 + (lane & 15);
            H4 hv;
#pragma unroll
            for (int r = 0; r < 4; ++r) {
                const float v = acc[mi][nj][r] * (1.f / 65536.f) + bs4.f[r];
                ps[mi * 4 + r][nj & 1] += v;
                hv.h[r] = (_Float16)v;
            }
            *(uint2*)&value_T[((size_t)b * 1024 + p) * 512 + obase] = hv.u;
        }
    }
#pragma unroll
    for (int q = 0; q < 16; ++q)
#pragma unroll
        for (int f2s = 0; f2s < 2; ++f2s) {
            ps[q][f2s] += __shfl_xor(ps[q][f2s], 1);
            ps[q][f2s] += __shfl_xor(ps[q][f2s], 2);
            ps[q][f2s] += __shfl_xor(ps[q][f2s], 4);
        }
    if ((lane & 7) == 0) {
#pragma unroll
        for (int mi = 0; mi < 4; ++mi)
#pragma unroll
            for (int r = 0; r < 4; ++r) {
                const int ol = wr * 64 + mi * 16 + (lane >> 4) * 4 + r;
                pool_lds[wc][ol][0 * 2 + pj] = ps[mi * 4 + r][0];
                pool_lds[wc][ol][1 * 2 + pj] = ps[mi * 4 + r][1];
            }
    }
    __syncthreads();
#pragma unroll
    for (int u = 0; u < 2; ++u) {
        const int idx = u * 256 + t;
        const int g = idx >> 7, o = idx & 127;
        centers_v[(((size_t)b * 8 + blockIdx.x) * 4 + g) * 512 + o0 + o] =
            pool_lds[0][o][g] + pool_lds[1][o][g];
    }
}

// ---------------- k_cluster: centers from partials, single feat stream ----------------
__global__ __launch_bounds__(256) void k_cluster(
    const float* __restrict__ feat_T, const _Float16* __restrict__ value_T,
    const float* __restrict__ centers_f, const float* __restrict__ centers_v,
    const float* __restrict__ alpha_p, const float* __restrict__ beta_p,
    _Float16* __restrict__ outpT, float* __restrict__ part)
{
    __shared__ _Float16 vbuf[256 * 64];   // idx n*64 + (c ^ ((n&7)<<3))
    __shared__ float cnl[4][64];
    __shared__ float vcl[4][64];
    __shared__ float obuf[4][68];
    __shared__ int   sidx[256];
    __shared__ float sbest[256];
    __shared__ float scrt[4][4][64];
    __shared__ int   cntw[4][4];
    __shared__ float red[8];
    __shared__ float gsc[16];

    const int t = threadIdx.x, lane = t & 63, wv = t >> 6;
    const int bp = blockIdx.x;
    const int f2 = bp & 1, f1 = (bp >> 1) & 1, head = (bp >> 2) & 7, b = bp >> 5;

    // ---- centers from GEMM-epilogue partials ----
    const int m = wv, cc = lane;
    const int pi = m >> 1, pj = m & 1, g = f2 * 2 + pj;
    const int pt = 4 * f1 + 2 * pi;
    {
        const float* cf = centers_f + (((size_t)b * 8 + pt) * 4 + g) * 512 + head * 64 + cc;
        const float c = (cf[0] + cf[4 * 512]) * (1.f / 64.f);
        float ss = c * c;
#pragma unroll
        for (int off = 32; off > 0; off >>= 1) ss += __shfl_xor(ss, off);
        const float inv = 1.f / fmaxf(sqrtf(ss), 1e-12f);
        cnl[m][cc] = c * inv;
        const float* cv = centers_v + (((size_t)b * 8 + pt) * 4 + g) * 512 + head * 64 + cc;
        vcl[m][cc] = (cv[0] + cv[4 * 512]) * (1.f / 64.f);
    }
    __syncthreads();

    // ---- G / L_Orth partial ----
    if (t < 16) {
        const int gm = t >> 2, gk = t & 3;
        float gg = 0.f;
        for (int c = 0; c < 64; ++c) gg += cnl[gm][c] * cnl[gk][c];
        const float d = gg - (gm == gk ? 1.f : 0.f);
        gsc[t] = d * d;
    }

    // ---- per-point: stream feat_T once (contiguous 256B/point) ----
    const float alpha = alpha_p[0], beta = beta_p[0];
    const int n = t;
    const int pg = (f1 * 16 + (n >> 4)) * 32 + f2 * 16 + (n & 15);
    const float* fp = feat_T + ((size_t)b * 1024 + pg) * 512 + head * 64;
    float ssf = 0.f, d0 = 0.f, d1 = 0.f, d2 = 0.f, d3 = 0.f;
#pragma unroll
    for (int c4 = 0; c4 < 16; ++c4) {
        F4 fv;
        fv.v = *(const float4*)&fp[c4 * 4];
        const float4 c0 = *(const float4*)&cnl[0][c4 * 4];
        const float4 c1 = *(const float4*)&cnl[1][c4 * 4];
        const float4 c2 = *(const float4*)&cnl[2][c4 * 4];
        const float4 c3 = *(const float4*)&cnl[3][c4 * 4];
        ssf += fv.f[0]*fv.f[0] + fv.f[1]*fv.f[1] + fv.f[2]*fv.f[2] + fv.f[3]*fv.f[3];
        d0 += fv.f[0]*c0.x + fv.f[1]*c0.y + fv.f[2]*c0.z + fv.f[3]*c0.w;
        d1 += fv.f[0]*c1.x + fv.f[1]*c1.y + fv.f[2]*c1.z + fv.f[3]*c1.w;
        d2 += fv.f[0]*c2.x + fv.f[1]*c2.y + fv.f[2]*c2.z + fv.f[3]*c2.w;
        d3 += fv.f[0]*c3.x + fv.f[1]*c3.y + fv.f[2]*c3.z + fv.f[3]*c3.w;
    }
    const float invf = 1.f / fmaxf(sqrtf(ssf), 1e-12f);
    float simv[4];
    simv[0] = d0 * invf;
    simv[1] = d1 * invf;
    simv[2] = d2 * invf;
    simv[3] = d3 * invf;
#pragma unroll
    for (int mm = 0; mm < 4; ++mm)
        simv[mm] = 1.f / (1.f + expf(-(beta + alpha * simv[mm])));
    float best = simv[0], second = -1.f;
    int idx = 0;
#pragma unroll
    for (int mm = 1; mm < 4; ++mm) {
        if (simv[mm] > best) { second = best; best = simv[mm]; idx = mm; }
        else second = fmaxf(second, simv[mm]);
    }
    sidx[n] = idx;
    sbest[n] = best;

    // ---- stage value tile from value_T (contiguous 128B/point) ----
    const _Float16* vp = value_T + ((size_t)b * 1024 + pg) * 512 + head * 64;
#pragma unroll
    for (int j = 0; j < 8; ++j) {
        const uint4 v = *(const uint4*)&vp[j * 8];
        *(uint4*)&vbuf[n * 64 + ((j * 8) ^ ((n & 7) << 3))] = v;
    }

    // ---- loss partial reduce ----
    float bsum = best, s2sum = second;
#pragma unroll
    for (int off = 32; off > 0; off >>= 1) {
        bsum += __shfl_xor(bsum, off);
        s2sum += __shfl_xor(s2sum, off);
    }
    if (lane == 0) { red[wv] = bsum; red[4 + wv] = s2sum; }
    __syncthreads();   // covers gsc, red, sidx, sbest, vbuf
    if (t == 0) {
        part[bp]        = gsc[0] + gsc[1] + gsc[2] + gsc[3] + gsc[4] + gsc[5] + gsc[6] + gsc[7]
                        + gsc[8] + gsc[9] + gsc[10] + gsc[11] + gsc[12] + gsc[13] + gsc[14] + gsc[15];
        part[1024 + bp] = red[0] + red[1] + red[2] + red[3];
        part[2048 + bp] = red[4] + red[5] + red[6] + red[7];
    }

    // ---- agg scan (wave wv covers 64 points) ----
    {
        float ag0 = 0.f, ag1 = 0.f, ag2 = 0.f, ag3 = 0.f;
        int c0i = 0, c1i = 0, c2i = 0, c3i = 0;
        for (int j = 0; j < 64; ++j) {
            const int nn = wv * 64 + j;
            const int id = sidx[nn];
            const float v = (float)vbuf[nn * 64 + (cc ^ ((nn & 7) << 3))];
            ag0 += (id == 0) ? v : 0.f;  c0i += (id == 0);
            ag1 += (id == 1) ? v : 0.f;  c1i += (id == 1);
            ag2 += (id == 2) ? v : 0.f;  c2i += (id == 2);
            ag3 += (id == 3) ? v : 0.f;  c3i += (id == 3);
        }
        scrt[wv][0][cc] = ag0;
        scrt[wv][1][cc] = ag1;
        scrt[wv][2][cc] = ag2;
        scrt[wv][3][cc] = ag3;
        if (lane == 0) {
            cntw[wv][0] = c0i; cntw[wv][1] = c1i;
            cntw[wv][2] = c2i; cntw[wv][3] = c3i;
        }
    }
    __syncthreads();

    // ---- cluster outputs ----
    {
        const float a = scrt[0][m][cc] + scrt[1][m][cc] + scrt[2][m][cc] + scrt[3][m][cc];
        const int c = cntw[0][m] + cntw[1][m] + cntw[2][m] + cntw[3][m];
        obuf[m][cc] = (a + vcl[m][cc]) / (float)(c + 1);
    }
    __syncthreads();

    // ---- coalesced outpT write ----
    const int cch = (t & 3) * 16;
#pragma unroll
    for (int r = 0; r < 4; ++r) {
        const int nn = r * 64 + (t >> 2);
        const int id = sidx[nn];
        const float bs = sbest[nn];
        const int p = (f1 * 16 + (nn >> 4)) * 32 + f2 * 16 + (nn & 15);
        _Float16* dst = outpT + (((size_t)b * 8 + head) * 1024 + p) * 64 + cch;
        const float4 oa = *(const float4*)&obuf[id][cch];
        const float4 ob = *(const float4*)&obuf[id][cch + 4];
        const float4 oc = *(const float4*)&obuf[id][cch + 8];
        const float4 od = *(const float4*)&obuf[id][cch + 12];
        H8 w0, w1;
        w0.h[0] = (_Float16)(bs * oa.x); w0.h[1] = (_Float16)(bs * oa.y);
        w0.h[2] = (_Float16)(bs * oa.z); w0.h[3] = (_Float16)(bs * oa.w);
        w0.h[4] = (_Float16)(bs * ob.x); w0.h[5] = (_Float16)(bs * ob.y);
        w0.h[6] = (_Float16)(bs * ob.z); w0.h[7] = (_Float16)(bs * ob.w);
        w1.h[0] = (_Float16)(bs * oc.x); w1.h[1] = (_Float16)(bs * oc.y);
        w1.h[2] = (_Float16)(bs * oc.z); w1.h[3] = (_Float16)(bs * oc.w);
        w1.h[4] = (_Float16)(bs * od.x); w1.h[5] = (_Float16)(bs * od.y);
        w1.h[6] = (_Float16)(bs * od.z); w1.h[7] = (_Float16)(bs * od.w);
        *(uint4*)dst = w0.u;
        *(uint4*)(dst + 8) = w1.u;
    }
}

// ---------------- k_proj: MFMA GEMM over outpT + loss finalize (round-3) ----------------
__global__ __launch_bounds__(256) void k_proj(
    const float* __restrict__ w, const float* __restrict__ bias,
    const _Float16* __restrict__ outpT,
    const float* __restrict__ part,
    float* __restrict__ dout)
{
    __shared__ _Float16 Ah[128 * 32], Bh[128 * 32];
    __shared__ float fin[12];
    const int t = threadIdx.x, lane = t & 63, wv = t >> 6;

    if (blockIdx.x == 0 && blockIdx.y == 0 && blockIdx.z == 0) {
        float so = part[t] + part[t + 256] + part[t + 512] + part[t + 768];
        float sc = part[1024 + t] + part[1280 + t] + part[1536 + t] + part[1792 + t];
        float sp = part[2048 + t] + part[2304 + t] + part[2560 + t] + part[2816 + t];
#pragma unroll
        for (int off = 32; off > 0; off >>= 1) {
            so += __shfl_xor(so, off);
            sc += __shfl_xor(sc, off);
            sp += __shfl_xor(sp, off);
        }
        if (lane == 0) { fin[wv] = so; fin[4 + wv] = sc; fin[8 + wv] = sp; }
        __syncthreads();
        if (t == 0) {
            dout[16777216]     = (fin[0] + fin[1] + fin[2] + fin[3]) / 16384.f;
            dout[16777216 + 1] = -(fin[4] + fin[5] + fin[6] + fin[7]) / 262144.f;
            dout[16777216 + 2] = (fin[8] + fin[9] + fin[10] + fin[11]) / 262144.f;
        }
        __syncthreads();
    }

    const int b = blockIdx.z, o0 = blockIdx.y * 128, p0 = blockIdx.x * 128;
    const int wr = wv >> 1, wc = wv & 1;

    f32x4 acc[4][4];
#pragma unroll
    for (int i = 0; i < 4; ++i)
#pragma unroll
        for (int j = 0; j < 4; ++j) acc[i][j] = (f32x4){0.f, 0.f, 0.f, 0.f};

    const int srow = p0 + wv * 32 + (lane >> 2);
    const int scol = (lane & 3) * 8;

    for (int kb = 0; kb < 16; ++kb) {
        const int k0 = kb * 32;
        F4 av[4];
#pragma unroll
        for (int j = 0; j < 4; ++j) {
            const int idx = j * 256 + t, row = idx >> 3, q = idx & 7;
            av[j].v = *(const float4*)&w[(size_t)(o0 + row) * 512 + k0 + q * 4];
        }
        __syncthreads();
#pragma unroll
        for (int j = 0; j < 4; ++j) {
            const int idx = j * 256 + t, row = idx >> 3, q = idx & 7;
            H4 hh;
#pragma unroll
            for (int i = 0; i < 4; ++i) hh.h[i] = (_Float16)(av[j].f[i] * 256.f);
            *(uint2*)&Ah[row * 32 + q * 4] = hh.u;
        }
        const _Float16* bsrc = outpT + (((size_t)b * 8 + (kb >> 1)) * 1024 + srow) * 64
                               + (kb & 1) * 32 + scol;
        gld16(bsrc,            &Bh[(wv * 32) * 32]);
        gld16(bsrc + 16 * 64,  &Bh[(wv * 32 + 16) * 32]);
        __syncthreads();
        f16x8 ah[4], bh[4];
#pragma unroll
        for (int i = 0; i < 4; ++i) {
            ah[i] = *(f16x8*)&Ah[(wr * 64 + i * 16 + (lane & 15)) * 32 + (lane >> 4) * 8];
            bh[i] = *(f16x8*)&Bh[(wc * 64 + i * 16 + (lane & 15)) * 32 + (lane >> 4) * 8];
        }
#pragma unroll
        for (int mi = 0; mi < 4; ++mi)
#pragma unroll
            for (int nj = 0; nj < 4; ++nj)
                acc[mi][nj] = __builtin_amdgcn_mfma_f32_16x16x32_f16(ah[mi], bh[nj], acc[mi][nj], 0, 0, 0);
    }
#pragma unroll
    for (int mi = 0; mi < 4; ++mi)
#pragma unroll
        for (int r = 0; r < 4; ++r) {
            const int o = o0 + wr * 64 + mi * 16 + (lane >> 4) * 4 + r;
            const float bs = bias[o];
#pragma unroll
            for (int nj = 0; nj < 4; ++nj) {
                const int p = p0 + wc * 64 + nj * 16 + (lane & 15);
                dout[((size_t)b * 512 + o) * HW + p] = acc[mi][nj][r] * (1.f / 256.f) + bs;
            }
        }
}

extern "C" void kernel_launch(void* const* d_in, const int* in_sizes, int n_in,
                              void* d_out, int out_size, void* d_ws, size_t ws_size,
                              hipStream_t stream)
{
    const float* x   = (const float*)d_in[0];
    const float* f_w = (const float*)d_in[1];
    const float* f_b = (const float*)d_in[2];
    const float* v_w = (const float*)d_in[3];
    const float* v_b = (const float*)d_in[4];
    const float* p_w = (const float*)d_in[5];
    const float* p_b = (const float*)d_in[6];
    const float* s_a = (const float*)d_in[7];
    const float* s_b = (const float*)d_in[8];
    float* out = (float*)d_out;

    char* ws = (char*)d_ws;
    float*     feat_T  = (float*)ws;                                   // [0, 64M)
    _Float16*  xh      = (_Float16*)(ws + (size_t)64 * 1024 * 1024);   // [64M, 96M)
    _Float16*  xl      = (_Float16*)(ws + (size_t)96 * 1024 * 1024);   // [96M, 128M)
    _Float16*  outpT   = xh;                                           // reuse after k_value
    _Float16*  value_T = xl;                                           // reuse after k_feat
    float*     part    = (float*)(ws + (size_t)128 * 1024 * 1024);     // 12 KB

    // scratch in d_out (consumed before k_proj overwrites it)
    _Float16* fwh       = (_Float16*)out;                // 512 KB
    _Float16* fwl       = (_Float16*)(out + 131072);     // 512 KB
    _Float16* vwh       = (_Float16*)(out + 262144);     // 512 KB
    float*    centers_f = out + 393216;                  // 2 MB
    float*    centers_v = out + 917504;                  // 2 MB

    k_wsplit <<<dim3(256), 256, 0, stream>>>(f_w, v_w, fwh, fwl, vwh);
    k_xsplit <<<dim3(16, 8, 32), 256, 0, stream>>>(x, xh, xl);
    k_feat   <<<dim3(8, 4, 32), 256, 0, stream>>>(fwh, fwl, f_b, xh, xl, feat_T, centers_f);
    k_value  <<<dim3(8, 4, 32), 256, 0, stream>>>(vwh, v_b, xh, value_T, centers_v);
    k_cluster<<<dim3(1024), 256, 0, stream>>>(feat_T, value_T, centers_f, centers_v,
                                              s_a, s_b, outpT, part);
    k_proj   <<<dim3(8, 4, 32), 256, 0, stream>>>(p_w, p_b, outpT, part, out);
}